// Round 9
// baseline (966.392 us; speedup 1.0000x reference)
//
#include <hip/hip_runtime.h>
#include <hip/hip_bf16.h>
#include <cstdint>
#include <cstddef>

#define R_ 64
#define K_ 81
#define NPTS_ 784

typedef __attribute__((ext_vector_type(8))) short short8;
typedef __attribute__((ext_vector_type(4))) float f32x4;

#define GLDS16(G, L)                                                           \
  __builtin_amdgcn_global_load_lds(                                            \
      (__attribute__((address_space(1))) void*)(void*)(G),                     \
      (__attribute__((address_space(3))) void*)(L), 16, 0, 0)

// ---------------- transpose feat [C][H][W] -> [H][W][C] ----------------
__global__ __launch_bounds__(256) void transpose_feat_kernel(const float* __restrict__ in,
                                                             float* __restrict__ out) {
  __shared__ float tile[32][33];
  int y = blockIdx.z;
  int x0 = blockIdx.x * 32, c0 = blockIdx.y * 32;
  int tx = threadIdx.x, ty = threadIdx.y;
#pragma unroll
  for (int j = 0; j < 32; j += 8)
    tile[ty + j][tx] = in[(size_t)(c0 + ty + j) * 65536 + (size_t)y * 256 + x0 + tx];
  __syncthreads();
#pragma unroll
  for (int j = 0; j < 32; j += 8)
    out[((size_t)y * 256 + (x0 + ty + j)) * 256 + c0 + tx] = tile[tx][ty + j];
}

// ---------------- transpose coarse [R][K][49] -> [R][49][K] ----------------
__global__ void transpose_coarse_kernel(const float* __restrict__ in, float* __restrict__ out) {
  int t = blockIdx.x * 256 + threadIdx.x;
  if (t >= R_ * 49 * K_) return;
  int k = t % K_;
  int t2 = t / K_;
  int pos = t2 % 49;
  int r = t2 / 49;
  out[t] = in[((size_t)r * K_ + k) * 49 + pos];
}

// ---------------- pack W into MFMA-fragment-linear layout (hi/lo bf16) ----------------
__global__ void prep_wpack_kernel(const float* __restrict__ W1, const float* __restrict__ W2,
                                  const float* __restrict__ W3, const float* __restrict__ Wp,
                                  const float* __restrict__ b1, const float* __restrict__ b2,
                                  const float* __restrict__ b3, const float* __restrict__ bp,
                                  __hip_bfloat16* __restrict__ Wpk, float* __restrict__ bias_all) {
  int t = blockIdx.x * 256 + threadIdx.x;
  if (t < 90112) {
    int lane = t & 63;
    int t2 = t >> 6;
    int hl = t2 & 1;
    t2 >>= 1;
    int jg = t2 & 15;
    t2 >>= 4;
    int kt = t2 % 11;
    int L = t2 / 11;
    int o = jg * 16 + (lane & 15);
    int kbase = kt * 32 + (lane >> 4) * 8;
    const float* Wsrc = (L == 0) ? W1 : (L == 1) ? W2 : (L == 2) ? W3 : Wp;
    int Omax = (L == 3) ? 81 : 256;
    __hip_bfloat16 outv[8];
#pragma unroll
    for (int e = 0; e < 8; ++e) {
      int k = kbase + e;
      float v = (o < Omax && k < 337) ? Wsrc[o * 337 + k] : 0.f;
      __hip_bfloat16 h = __float2bfloat16(v);
      outv[e] = hl ? __float2bfloat16(v - __bfloat162float(h)) : h;
    }
    *(short8*)(Wpk + (size_t)t * 8) = *(const short8*)outv;
  } else if (t < 90112 + 1024) {
    int k = t - 90112;
    float v = 0.f;
    if (k < 256) v = b1[k];
    else if (k < 512) v = b2[k - 256];
    else if (k < 768) v = b3[k - 512];
    else if (k < 768 + 81) v = bp[k - 768];
    bias_all[k] = v;
  }
}

// ---------------- 2x bilinear upsample, quad form ----------------
__global__ __launch_bounds__(128) void upsample2x_kernel(const float* __restrict__ in,
                                                         float* __restrict__ out,
                                                         int Hin, int Win) {
  int b = blockIdx.z;
  int iy = blockIdx.y * 2 + threadIdx.y;
  int ix = blockIdx.x * 64 + threadIdx.x;
  if (ix >= Win || iy >= Hin) return;
  const float* p = in + (size_t)b * Hin * Win;
  int rT = (iy == 0) ? 0 : iy - 1;
  int rB = (iy == Hin - 1) ? iy : iy + 1;
  int cL = (ix == 0) ? 0 : ix - 1;
  int cR = (ix == Win - 1) ? ix : ix + 1;
  float wyT1 = (iy == 0) ? 0.f : 0.75f;
  float wyB1 = (iy == Hin - 1) ? 0.f : 0.25f;
  float wxE1 = (ix == 0) ? 0.f : 0.75f;
  float wxO1 = (ix == Win - 1) ? 0.f : 0.25f;
  float wyT0 = 1.f - wyT1, wyB0 = 1.f - wyB1;
  float wxE0 = 1.f - wxE1, wxO0 = 1.f - wxO1;

  const float* rowA = p + (size_t)rT * Win;
  const float* rowM = p + (size_t)iy * Win;
  const float* rowC = p + (size_t)rB * Win;
  float al = rowA[cL], am = rowA[ix], ar = rowA[cR];
  float mL = rowM[cL], mm = rowM[ix], mr = rowM[cR];
  float cl = rowC[cL], cm = rowC[ix], cr = rowC[cR];

  float aE = wxE0 * al + wxE1 * am;
  float aO = wxO0 * am + wxO1 * ar;
  float mE = wxE0 * mL + wxE1 * mm;
  float mO = wxO0 * mm + wxO1 * mr;
  float cE = wxE0 * cl + wxE1 * cm;
  float cO = wxO0 * cm + wxO1 * cr;

  float oTE = wyT0 * aE + wyT1 * mE;
  float oTO = wyT0 * aO + wyT1 * mO;
  float oBE = wyB0 * mE + wyB1 * cE;
  float oBO = wyB0 * mO + wyB1 * cO;

  int Wout = 2 * Win;
  float* ob = out + ((size_t)b * (2 * Hin) + 2 * iy) * Wout + 2 * ix;
  *(float2*)ob = make_float2(oTE, oTO);
  *(float2*)(ob + Wout) = make_float2(oBE, oBO);
}

// ---------------- iota selection (step 1: all 784 points) ----------------
__global__ void iota_kernel(int* __restrict__ sel) {
  int t = blockIdx.x * 256 + threadIdx.x;
  if (t < R_ * NPTS_) sel[t] = t % NPTS_;
}

// ---------------- per-ROI top-784 smallest |gt| (jax top_k tie semantics) ----------------
__global__ __launch_bounds__(256) void topk_kernel(const float* __restrict__ ml,
                                                   const int* __restrict__ labels,
                                                   int N, int* __restrict__ sel) {
  int r = blockIdx.x;
  const float* gt = ml + ((size_t)r * K_ + (labels[r] + 1)) * N;
  __shared__ unsigned int hist[256];
  __shared__ unsigned int sh_prefix, sh_remaining, sh_countless;
  int tid = threadIdx.x;

  unsigned int prefix = 0;
  unsigned int remaining = NPTS_;
  unsigned int count_less = 0;
  for (int pass = 0; pass < 4; ++pass) {
    int shift = 24 - 8 * pass;
    hist[tid] = 0;
    __syncthreads();
    for (int i = tid; i < N; i += 256) {
      unsigned int v = __float_as_uint(fabsf(gt[i]));
      bool match = (pass == 0) || ((v >> (shift + 8)) == prefix);
      if (match) atomicAdd(&hist[(v >> shift) & 255u], 1u);
    }
    __syncthreads();
    if (tid == 0) {
      unsigned int cum = 0, before = 0;
      int d = 255;
      for (int dd = 0; dd < 256; ++dd) {
        unsigned int c = hist[dd];
        if (cum + c >= remaining) { before = cum; d = dd; break; }
        cum += c;
      }
      sh_prefix = (prefix << 8) | (unsigned int)d;
      sh_remaining = remaining - before;
      sh_countless = count_less + before;
    }
    __syncthreads();
    prefix = sh_prefix;
    remaining = sh_remaining;
    count_less = sh_countless;
    __syncthreads();
  }
  unsigned int vstar = prefix;
  unsigned int need_eq = NPTS_ - count_less;

  __shared__ unsigned int wtot_less[4], wtot_eq[4];
  unsigned int base_less = 0, base_eq = 0;
  int lane = tid & 63, wv = tid >> 6;
  int* selr = sel + (size_t)r * NPTS_;
  for (int base = 0; base < N; base += 256) {
    int i = base + tid;
    bool less = false, eq = false;
    if (i < N) {
      unsigned int v = __float_as_uint(fabsf(gt[i]));
      less = v < vstar;
      eq = v == vstar;
    }
    unsigned long long ml_ = __ballot(less);
    unsigned long long me_ = __ballot(eq);
    unsigned long long lanemask = (lane == 0) ? 0ull : ((~0ull) >> (64 - lane));
    unsigned int pl = __popcll(ml_ & lanemask);
    unsigned int pe = __popcll(me_ & lanemask);
    if (lane == 0) { wtot_less[wv] = (unsigned int)__popcll(ml_); wtot_eq[wv] = (unsigned int)__popcll(me_); }
    __syncthreads();
    unsigned int off_l = 0, off_e = 0, tot_l = 0, tot_e = 0;
#pragma unroll
    for (int w2 = 0; w2 < 4; ++w2) {
      unsigned int tl = wtot_less[w2], te = wtot_eq[w2];
      if (w2 < wv) { off_l += tl; off_e += te; }
      tot_l += tl;
      tot_e += te;
    }
    if (less) selr[base_less + off_l + pl] = i;
    if (eq) {
      unsigned int er = base_eq + off_e + pe;
      if (er < need_eq) selr[count_less + er] = i;
    }
    base_less += tot_l;
    base_eq += tot_e;
    __syncthreads();
  }
}

// ---------------- sample fine + coarse; write hi/lo bf16 splits ----------------
__global__ __launch_bounds__(256) void sample_kernel(const int* __restrict__ sel,
                                                     const float* __restrict__ bboxes,
                                                     const float* __restrict__ featT,
                                                     const float* __restrict__ coarseT,
                                                     __hip_bfloat16* __restrict__ Xh,
                                                     __hip_bfloat16* __restrict__ Xl,
                                                     __hip_bfloat16* __restrict__ Cth,
                                                     __hip_bfloat16* __restrict__ Ctl,
                                                     int Wlev, int Hlev) {
  int rp = blockIdx.x;
  int r = rp / NPTS_;
  int idx = sel[rp];
  int tid = threadIdx.x;

  float px = ((float)(idx % Wlev) + 0.5f) / (float)Wlev;
  float py = ((float)(idx / Wlev) + 0.5f) / (float)Hlev;
  float bx0 = bboxes[r * 4 + 0], by0 = bboxes[r * 4 + 1];
  float bw = __fsub_rn(bboxes[r * 4 + 2], bx0);
  float bh = __fsub_rn(bboxes[r * 4 + 3], by0);
  float cx = __fadd_rn(bx0, __fmul_rn(px, bw));
  float cy = __fadd_rn(by0, __fmul_rn(py, bh));

  {
    float gx = __fsub_rn(__fmul_rn(cx, 0.25f), 0.5f);
    float gy = __fsub_rn(__fmul_rn(cy, 0.25f), 0.5f);
    float fxf = floorf(gx), fyf = floorf(gy);
    float fx = __fsub_rn(gx, fxf), fy = __fsub_rn(gy, fyf);
    int x0 = (int)fxf, y0 = (int)fyf;
    float ofx = __fsub_rn(1.f, fx), ofy = __fsub_rn(1.f, fy);
    float w00 = __fmul_rn(ofx, ofy);
    float w10 = __fmul_rn(fx, ofy);
    float w01 = __fmul_rn(ofx, fy);
    float w11 = __fmul_rn(fx, fy);
    bool vx0 = (x0 >= 0) && (x0 < 256), vx1 = (x0 + 1 >= 0) && (x0 + 1 < 256);
    bool vy0 = (y0 >= 0) && (y0 < 256), vy1 = (y0 + 1 >= 0) && (y0 + 1 < 256);
    float W00 = (vx0 && vy0) ? w00 : 0.f;
    float W10 = (vx1 && vy0) ? w10 : 0.f;
    float W01 = (vx0 && vy1) ? w01 : 0.f;
    float W11 = (vx1 && vy1) ? w11 : 0.f;
    int x0c = min(max(x0, 0), 255), x1c = min(max(x0 + 1, 0), 255);
    int y0c = min(max(y0, 0), 255), y1c = min(max(y0 + 1, 0), 255);
    const float* p00 = featT + ((size_t)(y0c * 256 + x0c)) * 256;
    const float* p10 = featT + ((size_t)(y0c * 256 + x1c)) * 256;
    const float* p01 = featT + ((size_t)(y1c * 256 + x0c)) * 256;
    const float* p11 = featT + ((size_t)(y1c * 256 + x1c)) * 256;
    float acc = __fmul_rn(p00[tid], W00);
    acc = __fadd_rn(acc, __fmul_rn(p10[tid], W10));
    acc = __fadd_rn(acc, __fmul_rn(p01[tid], W01));
    acc = __fadd_rn(acc, __fmul_rn(p11[tid], W11));
    __hip_bfloat16 h = __float2bfloat16(acc);
    Xh[(size_t)rp * 256 + tid] = h;
    Xl[(size_t)rp * 256 + tid] = __float2bfloat16(acc - __bfloat162float(h));
  }

  if (tid < 96) {
    float acc = 0.f;
    if (tid < K_) {
      float gx = __fsub_rn(__fmul_rn(px, 7.f), 0.5f);
      float gy = __fsub_rn(__fmul_rn(py, 7.f), 0.5f);
      float fxf = floorf(gx), fyf = floorf(gy);
      float fx = __fsub_rn(gx, fxf), fy = __fsub_rn(gy, fyf);
      int x0 = (int)fxf, y0 = (int)fyf;
      float ofx = __fsub_rn(1.f, fx), ofy = __fsub_rn(1.f, fy);
      float w00 = __fmul_rn(ofx, ofy);
      float w10 = __fmul_rn(fx, ofy);
      float w01 = __fmul_rn(ofx, fy);
      float w11 = __fmul_rn(fx, fy);
      bool vx0 = (x0 >= 0) && (x0 < 7), vx1 = (x0 + 1 >= 0) && (x0 + 1 < 7);
      bool vy0 = (y0 >= 0) && (y0 < 7), vy1 = (y0 + 1 >= 0) && (y0 + 1 < 7);
      float W00 = (vx0 && vy0) ? w00 : 0.f;
      float W10 = (vx1 && vy0) ? w10 : 0.f;
      float W01 = (vx0 && vy1) ? w01 : 0.f;
      float W11 = (vx1 && vy1) ? w11 : 0.f;
      int x0c = min(max(x0, 0), 6), x1c = min(max(x0 + 1, 0), 6);
      int y0c = min(max(y0, 0), 6), y1c = min(max(y0 + 1, 0), 6);
      const float* cb = coarseT + (size_t)r * 49 * K_;
      acc = __fmul_rn(cb[(size_t)(y0c * 7 + x0c) * K_ + tid], W00);
      acc = __fadd_rn(acc, __fmul_rn(cb[(size_t)(y0c * 7 + x1c) * K_ + tid], W10));
      acc = __fadd_rn(acc, __fmul_rn(cb[(size_t)(y1c * 7 + x0c) * K_ + tid], W01));
      acc = __fadd_rn(acc, __fmul_rn(cb[(size_t)(y1c * 7 + x1c) * K_ + tid], W11));
    }
    __hip_bfloat16 h = __float2bfloat16(acc);
    Cth[(size_t)rp * 96 + tid] = h;
    Ctl[(size_t)rp * 96 + tid] = __float2bfloat16(acc - __bfloat162float(h));
  }
}

// ---------------- FUSED 4-layer point head + scatter, v4 ----------------
// Block: 64 points x 256 out-cols, 4 waves. X staged once via GLDS16 (R7 layout:
// hi 11 chunks + lo chunks 0..7; coarse-lo frags straight from global Ct_l).
// W fragment-packed from global. k-loop: fully unrolled, ping-pong prefetch
// (W depth 2 for TERMS=1), setprio around MFMA clusters, no barriers.
// L==3 epilogue: bias + DIRECT scattered store into ml (fused scatter, no PL).
template <int TERMS>
__global__ __launch_bounds__(256, 2) void fused_head_kernel(
    const __hip_bfloat16* __restrict__ Ah, const __hip_bfloat16* __restrict__ Al,
    const __hip_bfloat16* __restrict__ Th, const __hip_bfloat16* __restrict__ Tl,
    const __hip_bfloat16* __restrict__ Wpk,
    const float* __restrict__ bias_all,
    const int* __restrict__ sel, float* __restrict__ ml, int Nlev) {
  constexpr int XPLANE = 11 * 4096;  // 45056 B (hi)
  constexpr int XLO = 8 * 4096;      // 32768 B (lo, activation chunks only)
  __shared__ char lds[(TERMS == 3) ? XPLANE + XLO : XPLANE];
  char* Xh = lds;
  char* Xl = lds + XPLANE;  // chunks 0..7 only; TERMS==3

  const int tid = threadIdx.x;
  const int lane = tid & 63;
  const int w = tid >> 6;
  const int g = lane >> 4;
  const int lane15 = lane & 15;
  const int m0 = blockIdx.x * 64;

  // ---- stage X once (pre-swizzled global source, linear LDS dest) ----
  {
    const int srow = tid >> 2;
    const int sp = tid & 3;
    const int sx = sp ^ ((srow >> 1) & 3);
#pragma unroll
    for (int kt = 0; kt < 8; ++kt) {
      size_t off = (((size_t)(m0 + srow)) * 256 + (size_t)kt * 32 + (size_t)sx * 8) * 2;
      GLDS16((const char*)Ah + off, Xh + kt * 4096 + w * 1024);
      if constexpr (TERMS == 3) GLDS16((const char*)Al + off, Xl + kt * 4096 + w * 1024);
    }
#pragma unroll
    for (int kt = 8; kt < 11; ++kt) {
      size_t off = (((size_t)(m0 + srow)) * 96 + (size_t)(kt - 8) * 32 + (size_t)sx * 8) * 2;
      GLDS16((const char*)Th + off, Xh + kt * 4096 + w * 1024);
    }
  }
  asm volatile("s_waitcnt vmcnt(0)" ::: "memory");
  __syncthreads();

  int offA[4];
#pragma unroll
  for (int i = 0; i < 4; ++i) {
    int rowA = i * 16 + lane15;
    offA[i] = rowA * 64 + ((g ^ ((rowA >> 1) & 3)) << 4);
  }

  constexpr int BD = (TERMS == 1) ? 3 : 2;  // W prefetch buffers

#pragma unroll 1
  for (int L = 0; L < 4; ++L) {
    if (L == 3 && w >= 2) break;  // Wp cols 128..255 all-zero
    const __hip_bfloat16* WL = Wpk + (size_t)L * (11 * 16 * 2 * 512);

    f32x4 acc[4][4];
#pragma unroll
    for (int i = 0; i < 4; ++i)
#pragma unroll
      for (int j = 0; j < 4; ++j) acc[i][j] = (f32x4){0.f, 0.f, 0.f, 0.f};

    short8 a_h[2][4], a_l[2][4], b_h[BD][4], b_l[BD][4];

    auto loadA = [&](int buf, int kt) {
#pragma unroll
      for (int i = 0; i < 4; ++i) {
        a_h[buf][i] = *(const short8*)(Xh + kt * 4096 + offA[i]);
        if constexpr (TERMS == 3) {
          if (kt < 8)
            a_l[buf][i] = *(const short8*)(Xl + kt * 4096 + offA[i]);
          else
            a_l[buf][i] = *(const short8*)((const char*)Tl +
                (((size_t)(m0 + i * 16 + lane15)) * 96 + (size_t)(kt - 8) * 32 +
                 (size_t)g * 8) * 2);
        }
      }
    };
    auto loadB = [&](int buf, int kt) {
#pragma unroll
      for (int j = 0; j < 4; ++j) {
        const __hip_bfloat16* bp =
            WL + (((size_t)kt * 16 + (w * 4 + j)) * 2) * 512 + (size_t)lane * 8;
        b_h[buf][j] = *(const short8*)bp;
        if constexpr (TERMS == 3) b_l[buf][j] = *(const short8*)(bp + 512);
      }
    };

    loadA(0, 0);
#pragma unroll
    for (int pb = 0; pb < BD - 1; ++pb) loadB(pb, pb);

#pragma unroll
    for (int kt = 0; kt < 11; ++kt) {
      const int ca = kt & 1;
      const int cb = kt % BD;
      if (kt < 10) loadA(ca ^ 1, kt + 1);
      if (kt + BD - 1 < 11) loadB((kt + BD - 1) % BD, kt + BD - 1);
      __builtin_amdgcn_s_setprio(1);
#pragma unroll
      for (int i = 0; i < 4; ++i)
#pragma unroll
        for (int j = 0; j < 4; ++j) {
          acc[i][j] = __builtin_amdgcn_mfma_f32_16x16x32_bf16(a_h[ca][i], b_h[cb][j], acc[i][j], 0, 0, 0);
          if constexpr (TERMS == 3) {
            acc[i][j] = __builtin_amdgcn_mfma_f32_16x16x32_bf16(a_h[ca][i], b_l[cb][j], acc[i][j], 0, 0, 0);
            acc[i][j] = __builtin_amdgcn_mfma_f32_16x16x32_bf16(a_l[ca][i], b_h[cb][j], acc[i][j], 0, 0, 0);
          }
        }
      __builtin_amdgcn_s_setprio(0);
    }

    if (L < 3) {
      __syncthreads();  // all waves done READING X before overwrite
#pragma unroll
      for (int j = 0; j < 4; ++j) {
        int o = w * 64 + j * 16 + lane15;
        float bv = bias_all[L * 256 + o];
        int kch = o >> 5;
        int s0 = (o >> 3) & 3;
        int e = o & 7;
#pragma unroll
        for (int i = 0; i < 4; ++i) {
          int mb = i * 16 + g * 4;
#pragma unroll
          for (int r = 0; r < 4; ++r) {
            int m = mb + r;
            float v = fmaxf(acc[i][j][r] + bv, 0.f);
            __hip_bfloat16 h = __float2bfloat16(v);
            int boff = kch * 4096 + m * 64 + ((s0 ^ ((m >> 1) & 3)) << 4) + e * 2;
            *(__hip_bfloat16*)(Xh + boff) = h;
            if constexpr (TERMS == 3)
              *(__hip_bfloat16*)(Xl + boff) = __float2bfloat16(v - __bfloat162float(h));
          }
        }
      }
      __syncthreads();
    } else {
      // fused scatter: bias + direct store into ml (waves 0,1 only)
#pragma unroll
      for (int j = 0; j < 4; ++j) {
        int o = w * 64 + j * 16 + lane15;
        if (o < K_) {
          float bv = bias_all[768 + o];
#pragma unroll
          for (int i = 0; i < 4; ++i) {
            int mb = i * 16 + g * 4;
#pragma unroll
            for (int r = 0; r < 4; ++r) {
              int m = m0 + mb + r;
              int idx = sel[m];
              int rroi = m / NPTS_;
              ml[((size_t)rroi * K_ + o) * Nlev + idx] = acc[i][j][r] + bv;
            }
          }
        }
      }
    }
  }
}

extern "C" void kernel_launch(void* const* d_in, const int* in_sizes, int n_in,
                              void* d_out, int out_size, void* d_ws, size_t ws_size,
                              hipStream_t stream) {
  (void)in_sizes; (void)n_in; (void)out_size; (void)ws_size;
  const float* feat = (const float*)d_in[0];
  const float* bboxes = (const float*)d_in[1];
  const int* labels = (const int*)d_in[2];
  const float* coarse = (const float*)d_in[3];
  const float* W1 = (const float*)d_in[4];
  const float* b1 = (const float*)d_in[5];
  const float* W2 = (const float*)d_in[6];
  const float* b2 = (const float*)d_in[7];
  const float* W3 = (const float*)d_in[8];
  const float* b3 = (const float*)d_in[9];
  const float* Wp = (const float*)d_in[10];
  const float* bp = (const float*)d_in[11];
  float* out = (float*)d_out;

  char* p = (char*)d_ws;
  auto alloc = [&](size_t bytes) { char* r = p; p += (bytes + 255) & ~(size_t)255; return r; };
  float* featT = (float*)alloc(16777216ull * 4);
  float* coarseT = (float*)alloc(254016ull * 4);
  float* ml14 = (float*)alloc(1016064ull * 4);
  float* ml28 = (float*)alloc(4064256ull * 4);
  float* ml56 = (float*)alloc(16257024ull * 4);
  int* sel = (int*)alloc(50176ull * 4);
  __hip_bfloat16* Xa_h = (__hip_bfloat16*)alloc(12845056ull * 2);
  __hip_bfloat16* Xa_l = (__hip_bfloat16*)alloc(12845056ull * 2);
  __hip_bfloat16* Ct_h = (__hip_bfloat16*)alloc(4816896ull * 2);
  __hip_bfloat16* Ct_l = (__hip_bfloat16*)alloc(4816896ull * 2);
  __hip_bfloat16* Wpk = (__hip_bfloat16*)alloc(720896ull * 2);  // 4*11*16*2*64*8
  float* bias_all = (float*)alloc(1024ull * 4);

  const int N = R_ * NPTS_;  // 50176
  const int B = R_ * K_;     // 5184

  transpose_feat_kernel<<<dim3(8, 8, 256), dim3(32, 8), 0, stream>>>(feat, featT);
  transpose_coarse_kernel<<<3969, 256, 0, stream>>>(coarse, coarseT);
  prep_wpack_kernel<<<357, 256, 0, stream>>>(W1, W2, W3, Wp, b1, b2, b3, bp, Wpk, bias_all);

  // step 0: 7 -> 14 (no refine)
  upsample2x_kernel<<<dim3(1, 4, B), dim3(64, 2), 0, stream>>>(coarse, ml14, 7, 7);

  // ---- step 1: 14 -> 28, refine ALL 784 points (exact 3-term head) ----
  upsample2x_kernel<<<dim3(1, 7, B), dim3(64, 2), 0, stream>>>(ml14, ml28, 14, 14);
  iota_kernel<<<196, 256, 0, stream>>>(sel);
  sample_kernel<<<N, 256, 0, stream>>>(sel, bboxes, featT, coarseT, Xa_h, Xa_l, Ct_h, Ct_l, 28, 28);
  fused_head_kernel<3><<<784, 256, 0, stream>>>(Xa_h, Xa_l, Ct_h, Ct_l, Wpk, bias_all, sel, ml28, 784);

  // ---- step 2: 28 -> 56, refine top-784 of 3136 (exact 3-term head) ----
  upsample2x_kernel<<<dim3(1, 14, B), dim3(64, 2), 0, stream>>>(ml28, ml56, 28, 28);
  topk_kernel<<<R_, 256, 0, stream>>>(ml56, labels, 3136, sel);
  sample_kernel<<<N, 256, 0, stream>>>(sel, bboxes, featT, coarseT, Xa_h, Xa_l, Ct_h, Ct_l, 56, 56);
  fused_head_kernel<3><<<784, 256, 0, stream>>>(Xa_h, Xa_l, Ct_h, Ct_l, Wpk, bias_all, sel, ml56, 3136);

  // ---- step 3: 56 -> 112 (into d_out), refine top-784 of 12544 (1-term bf16 head) ----
  upsample2x_kernel<<<dim3(1, 28, B), dim3(64, 2), 0, stream>>>(ml56, out, 56, 56);
  topk_kernel<<<R_, 256, 0, stream>>>(out, labels, 12544, sel);
  sample_kernel<<<N, 256, 0, stream>>>(sel, bboxes, featT, coarseT, Xa_h, Xa_l, Ct_h, Ct_l, 112, 112);
  fused_head_kernel<1><<<784, 256, 0, stream>>>(Xa_h, nullptr, Ct_h, nullptr, Wpk, bias_all, sel, out, 12544);
}

// Round 10
// 913.697 us; speedup vs baseline: 1.0577x; 1.0577x over previous
//
#include <hip/hip_runtime.h>
#include <hip/hip_bf16.h>
#include <cstdint>
#include <cstddef>

#define R_ 64
#define K_ 81
#define NPTS_ 784

typedef __attribute__((ext_vector_type(8))) short short8;
typedef __attribute__((ext_vector_type(4))) float f32x4;

#define GLDS16(G, L)                                                           \
  __builtin_amdgcn_global_load_lds(                                            \
      (__attribute__((address_space(1))) void*)(void*)(G),                     \
      (__attribute__((address_space(3))) void*)(L), 16, 0, 0)

// ---------------- transpose feat [C][H][W] -> [H][W][C] ----------------
__global__ __launch_bounds__(256) void transpose_feat_kernel(const float* __restrict__ in,
                                                             float* __restrict__ out) {
  __shared__ float tile[32][33];
  int y = blockIdx.z;
  int x0 = blockIdx.x * 32, c0 = blockIdx.y * 32;
  int tx = threadIdx.x, ty = threadIdx.y;
#pragma unroll
  for (int j = 0; j < 32; j += 8)
    tile[ty + j][tx] = in[(size_t)(c0 + ty + j) * 65536 + (size_t)y * 256 + x0 + tx];
  __syncthreads();
#pragma unroll
  for (int j = 0; j < 32; j += 8)
    out[((size_t)y * 256 + (x0 + ty + j)) * 256 + c0 + tx] = tile[tx][ty + j];
}

// ---------------- transpose coarse [R][K][49] -> [R][49][K] ----------------
__global__ void transpose_coarse_kernel(const float* __restrict__ in, float* __restrict__ out) {
  int t = blockIdx.x * 256 + threadIdx.x;
  if (t >= R_ * 49 * K_) return;
  int k = t % K_;
  int t2 = t / K_;
  int pos = t2 % 49;
  int r = t2 / 49;
  out[t] = in[((size_t)r * K_ + k) * 49 + pos];
}

// ---------------- pack W into MFMA-fragment-linear layout (hi/lo bf16) ----------------
__global__ void prep_wpack_kernel(const float* __restrict__ W1, const float* __restrict__ W2,
                                  const float* __restrict__ W3, const float* __restrict__ Wp,
                                  const float* __restrict__ b1, const float* __restrict__ b2,
                                  const float* __restrict__ b3, const float* __restrict__ bp,
                                  __hip_bfloat16* __restrict__ Wpk, float* __restrict__ bias_all) {
  int t = blockIdx.x * 256 + threadIdx.x;
  if (t < 90112) {
    int lane = t & 63;
    int t2 = t >> 6;
    int hl = t2 & 1;
    t2 >>= 1;
    int jg = t2 & 15;
    t2 >>= 4;
    int kt = t2 % 11;
    int L = t2 / 11;
    int o = jg * 16 + (lane & 15);
    int kbase = kt * 32 + (lane >> 4) * 8;
    const float* Wsrc = (L == 0) ? W1 : (L == 1) ? W2 : (L == 2) ? W3 : Wp;
    int Omax = (L == 3) ? 81 : 256;
    __hip_bfloat16 outv[8];
#pragma unroll
    for (int e = 0; e < 8; ++e) {
      int k = kbase + e;
      float v = (o < Omax && k < 337) ? Wsrc[o * 337 + k] : 0.f;
      __hip_bfloat16 h = __float2bfloat16(v);
      outv[e] = hl ? __float2bfloat16(v - __bfloat162float(h)) : h;
    }
    *(short8*)(Wpk + (size_t)t * 8) = *(const short8*)outv;
  } else if (t < 90112 + 1024) {
    int k = t - 90112;
    float v = 0.f;
    if (k < 256) v = b1[k];
    else if (k < 512) v = b2[k - 256];
    else if (k < 768) v = b3[k - 512];
    else if (k < 768 + 81) v = bp[k - 768];
    bias_all[k] = v;
  }
}

// ---------------- 2x bilinear upsample, quad form ----------------
__global__ __launch_bounds__(128) void upsample2x_kernel(const float* __restrict__ in,
                                                         float* __restrict__ out,
                                                         int Hin, int Win) {
  int b = blockIdx.z;
  int iy = blockIdx.y * 2 + threadIdx.y;
  int ix = blockIdx.x * 64 + threadIdx.x;
  if (ix >= Win || iy >= Hin) return;
  const float* p = in + (size_t)b * Hin * Win;
  int rT = (iy == 0) ? 0 : iy - 1;
  int rB = (iy == Hin - 1) ? iy : iy + 1;
  int cL = (ix == 0) ? 0 : ix - 1;
  int cR = (ix == Win - 1) ? ix : ix + 1;
  float wyT1 = (iy == 0) ? 0.f : 0.75f;
  float wyB1 = (iy == Hin - 1) ? 0.f : 0.25f;
  float wxE1 = (ix == 0) ? 0.f : 0.75f;
  float wxO1 = (ix == Win - 1) ? 0.f : 0.25f;
  float wyT0 = 1.f - wyT1, wyB0 = 1.f - wyB1;
  float wxE0 = 1.f - wxE1, wxO0 = 1.f - wxO1;

  const float* rowA = p + (size_t)rT * Win;
  const float* rowM = p + (size_t)iy * Win;
  const float* rowC = p + (size_t)rB * Win;
  float al = rowA[cL], am = rowA[ix], ar = rowA[cR];
  float mL = rowM[cL], mm = rowM[ix], mr = rowM[cR];
  float cl = rowC[cL], cm = rowC[ix], cr = rowC[cR];

  float aE = wxE0 * al + wxE1 * am;
  float aO = wxO0 * am + wxO1 * ar;
  float mE = wxE0 * mL + wxE1 * mm;
  float mO = wxO0 * mm + wxO1 * mr;
  float cE = wxE0 * cl + wxE1 * cm;
  float cO = wxO0 * cm + wxO1 * cr;

  float oTE = wyT0 * aE + wyT1 * mE;
  float oTO = wyT0 * aO + wyT1 * mO;
  float oBE = wyB0 * mE + wyB1 * cE;
  float oBO = wyB0 * mO + wyB1 * cO;

  int Wout = 2 * Win;
  float* ob = out + ((size_t)b * (2 * Hin) + 2 * iy) * Wout + 2 * ix;
  *(float2*)ob = make_float2(oTE, oTO);
  *(float2*)(ob + Wout) = make_float2(oBE, oBO);
}

// ---------------- iota selection (step 1: all 784 points) ----------------
__global__ void iota_kernel(int* __restrict__ sel) {
  int t = blockIdx.x * 256 + threadIdx.x;
  if (t < R_ * NPTS_) sel[t] = t % NPTS_;
}

// ---------------- per-ROI top-784 smallest |gt| (jax top_k tie semantics) ----------------
__global__ __launch_bounds__(256) void topk_kernel(const float* __restrict__ ml,
                                                   const int* __restrict__ labels,
                                                   int N, int* __restrict__ sel) {
  int r = blockIdx.x;
  const float* gt = ml + ((size_t)r * K_ + (labels[r] + 1)) * N;
  __shared__ unsigned int hist[256];
  __shared__ unsigned int sh_prefix, sh_remaining, sh_countless;
  int tid = threadIdx.x;

  unsigned int prefix = 0;
  unsigned int remaining = NPTS_;
  unsigned int count_less = 0;
  for (int pass = 0; pass < 4; ++pass) {
    int shift = 24 - 8 * pass;
    hist[tid] = 0;
    __syncthreads();
    for (int i = tid; i < N; i += 256) {
      unsigned int v = __float_as_uint(fabsf(gt[i]));
      bool match = (pass == 0) || ((v >> (shift + 8)) == prefix);
      if (match) atomicAdd(&hist[(v >> shift) & 255u], 1u);
    }
    __syncthreads();
    if (tid == 0) {
      unsigned int cum = 0, before = 0;
      int d = 255;
      for (int dd = 0; dd < 256; ++dd) {
        unsigned int c = hist[dd];
        if (cum + c >= remaining) { before = cum; d = dd; break; }
        cum += c;
      }
      sh_prefix = (prefix << 8) | (unsigned int)d;
      sh_remaining = remaining - before;
      sh_countless = count_less + before;
    }
    __syncthreads();
    prefix = sh_prefix;
    remaining = sh_remaining;
    count_less = sh_countless;
    __syncthreads();
  }
  unsigned int vstar = prefix;
  unsigned int need_eq = NPTS_ - count_less;

  __shared__ unsigned int wtot_less[4], wtot_eq[4];
  unsigned int base_less = 0, base_eq = 0;
  int lane = tid & 63, wv = tid >> 6;
  int* selr = sel + (size_t)r * NPTS_;
  for (int base = 0; base < N; base += 256) {
    int i = base + tid;
    bool less = false, eq = false;
    if (i < N) {
      unsigned int v = __float_as_uint(fabsf(gt[i]));
      less = v < vstar;
      eq = v == vstar;
    }
    unsigned long long ml_ = __ballot(less);
    unsigned long long me_ = __ballot(eq);
    unsigned long long lanemask = (lane == 0) ? 0ull : ((~0ull) >> (64 - lane));
    unsigned int pl = __popcll(ml_ & lanemask);
    unsigned int pe = __popcll(me_ & lanemask);
    if (lane == 0) { wtot_less[wv] = (unsigned int)__popcll(ml_); wtot_eq[wv] = (unsigned int)__popcll(me_); }
    __syncthreads();
    unsigned int off_l = 0, off_e = 0, tot_l = 0, tot_e = 0;
#pragma unroll
    for (int w2 = 0; w2 < 4; ++w2) {
      unsigned int tl = wtot_less[w2], te = wtot_eq[w2];
      if (w2 < wv) { off_l += tl; off_e += te; }
      tot_l += tl;
      tot_e += te;
    }
    if (less) selr[base_less + off_l + pl] = i;
    if (eq) {
      unsigned int er = base_eq + off_e + pe;
      if (er < need_eq) selr[count_less + er] = i;
    }
    base_less += tot_l;
    base_eq += tot_e;
    __syncthreads();
  }
}

// ---------------- sample fine + coarse; write hi/lo bf16 splits ----------------
__global__ __launch_bounds__(256) void sample_kernel(const int* __restrict__ sel,
                                                     const float* __restrict__ bboxes,
                                                     const float* __restrict__ featT,
                                                     const float* __restrict__ coarseT,
                                                     __hip_bfloat16* __restrict__ Xh,
                                                     __hip_bfloat16* __restrict__ Xl,
                                                     __hip_bfloat16* __restrict__ Cth,
                                                     __hip_bfloat16* __restrict__ Ctl,
                                                     int Wlev, int Hlev) {
  int rp = blockIdx.x;
  int r = rp / NPTS_;
  int idx = sel[rp];
  int tid = threadIdx.x;

  float px = ((float)(idx % Wlev) + 0.5f) / (float)Wlev;
  float py = ((float)(idx / Wlev) + 0.5f) / (float)Hlev;
  float bx0 = bboxes[r * 4 + 0], by0 = bboxes[r * 4 + 1];
  float bw = __fsub_rn(bboxes[r * 4 + 2], bx0);
  float bh = __fsub_rn(bboxes[r * 4 + 3], by0);
  float cx = __fadd_rn(bx0, __fmul_rn(px, bw));
  float cy = __fadd_rn(by0, __fmul_rn(py, bh));

  {
    float gx = __fsub_rn(__fmul_rn(cx, 0.25f), 0.5f);
    float gy = __fsub_rn(__fmul_rn(cy, 0.25f), 0.5f);
    float fxf = floorf(gx), fyf = floorf(gy);
    float fx = __fsub_rn(gx, fxf), fy = __fsub_rn(gy, fyf);
    int x0 = (int)fxf, y0 = (int)fyf;
    float ofx = __fsub_rn(1.f, fx), ofy = __fsub_rn(1.f, fy);
    float w00 = __fmul_rn(ofx, ofy);
    float w10 = __fmul_rn(fx, ofy);
    float w01 = __fmul_rn(ofx, fy);
    float w11 = __fmul_rn(fx, fy);
    bool vx0 = (x0 >= 0) && (x0 < 256), vx1 = (x0 + 1 >= 0) && (x0 + 1 < 256);
    bool vy0 = (y0 >= 0) && (y0 < 256), vy1 = (y0 + 1 >= 0) && (y0 + 1 < 256);
    float W00 = (vx0 && vy0) ? w00 : 0.f;
    float W10 = (vx1 && vy0) ? w10 : 0.f;
    float W01 = (vx0 && vy1) ? w01 : 0.f;
    float W11 = (vx1 && vy1) ? w11 : 0.f;
    int x0c = min(max(x0, 0), 255), x1c = min(max(x0 + 1, 0), 255);
    int y0c = min(max(y0, 0), 255), y1c = min(max(y0 + 1, 0), 255);
    const float* p00 = featT + ((size_t)(y0c * 256 + x0c)) * 256;
    const float* p10 = featT + ((size_t)(y0c * 256 + x1c)) * 256;
    const float* p01 = featT + ((size_t)(y1c * 256 + x0c)) * 256;
    const float* p11 = featT + ((size_t)(y1c * 256 + x1c)) * 256;
    float acc = __fmul_rn(p00[tid], W00);
    acc = __fadd_rn(acc, __fmul_rn(p10[tid], W10));
    acc = __fadd_rn(acc, __fmul_rn(p01[tid], W01));
    acc = __fadd_rn(acc, __fmul_rn(p11[tid], W11));
    __hip_bfloat16 h = __float2bfloat16(acc);
    Xh[(size_t)rp * 256 + tid] = h;
    Xl[(size_t)rp * 256 + tid] = __float2bfloat16(acc - __bfloat162float(h));
  }

  if (tid < 96) {
    float acc = 0.f;
    if (tid < K_) {
      float gx = __fsub_rn(__fmul_rn(px, 7.f), 0.5f);
      float gy = __fsub_rn(__fmul_rn(py, 7.f), 0.5f);
      float fxf = floorf(gx), fyf = floorf(gy);
      float fx = __fsub_rn(gx, fxf), fy = __fsub_rn(gy, fyf);
      int x0 = (int)fxf, y0 = (int)fyf;
      float ofx = __fsub_rn(1.f, fx), ofy = __fsub_rn(1.f, fy);
      float w00 = __fmul_rn(ofx, ofy);
      float w10 = __fmul_rn(fx, ofy);
      float w01 = __fmul_rn(ofx, fy);
      float w11 = __fmul_rn(fx, fy);
      bool vx0 = (x0 >= 0) && (x0 < 7), vx1 = (x0 + 1 >= 0) && (x0 + 1 < 7);
      bool vy0 = (y0 >= 0) && (y0 < 7), vy1 = (y0 + 1 >= 0) && (y0 + 1 < 7);
      float W00 = (vx0 && vy0) ? w00 : 0.f;
      float W10 = (vx1 && vy0) ? w10 : 0.f;
      float W01 = (vx0 && vy1) ? w01 : 0.f;
      float W11 = (vx1 && vy1) ? w11 : 0.f;
      int x0c = min(max(x0, 0), 6), x1c = min(max(x0 + 1, 0), 6);
      int y0c = min(max(y0, 0), 6), y1c = min(max(y0 + 1, 0), 6);
      const float* cb = coarseT + (size_t)r * 49 * K_;
      acc = __fmul_rn(cb[(size_t)(y0c * 7 + x0c) * K_ + tid], W00);
      acc = __fadd_rn(acc, __fmul_rn(cb[(size_t)(y0c * 7 + x1c) * K_ + tid], W10));
      acc = __fadd_rn(acc, __fmul_rn(cb[(size_t)(y1c * 7 + x0c) * K_ + tid], W01));
      acc = __fadd_rn(acc, __fmul_rn(cb[(size_t)(y1c * 7 + x1c) * K_ + tid], W11));
    }
    __hip_bfloat16 h = __float2bfloat16(acc);
    Cth[(size_t)rp * 96 + tid] = h;
    Ctl[(size_t)rp * 96 + tid] = __float2bfloat16(acc - __bfloat162float(h));
  }
}

// ---------------- FUSED 4-layer point head, v5: 8 waves x (32 pts x 64 cols) ----------------
// Block: 64 points x 256 out-cols, 512 threads. Wave w: point-group pg=w>>2 (32 pts),
// col-group cg=w&3 (64 cols). acc[2][4] (32 VGPR), A read direct from LDS per chunk
// (16 VGPR, latency hidden by >=2 waves/SIMD), B (global Wpk, L1/L2-hit) 2-deep
// ping-pong (64 VGPR) -> true prefetch fits the 128-VGPR tier (R7's 4x4 tile needed
// ~200 and got silently serialized at 128). Same MFMA sequence per element.
template <int TERMS>
__global__ __launch_bounds__(512, 2) void fused_head_kernel(
    const __hip_bfloat16* __restrict__ Ah, const __hip_bfloat16* __restrict__ Al,
    const __hip_bfloat16* __restrict__ Th, const __hip_bfloat16* __restrict__ Tl,
    const __hip_bfloat16* __restrict__ Wpk,
    const float* __restrict__ bias_all, float* __restrict__ PL) {
  constexpr int XPLANE = 11 * 4096;  // 45056 B (hi)
  constexpr int XLO = 8 * 4096;      // 32768 B (lo, activation chunks only)
  __shared__ char lds[(TERMS == 3) ? XPLANE + XLO : XPLANE];
  char* Xh = lds;
  char* Xl = lds + XPLANE;  // chunks 0..7 only; TERMS==3

  const int tid = threadIdx.x;  // 0..511
  const int lane = tid & 63;
  const int w = tid >> 6;       // 0..7
  const int pg = w >> 2;        // point group: 32 rows
  const int cg = w & 3;         // col group: 64 cols
  const int g = lane >> 4;
  const int lane15 = lane & 15;
  const int m0 = blockIdx.x * 64;

  // ---- stage X once: waves 0-3 stage hi plane, waves 4-7 stage lo plane ----
  {
    const int half = tid >> 8;       // 0/1 (wave-uniform)
    const int t2 = tid & 255;
    const int w4 = t2 >> 6;
    const int srow = t2 >> 2;
    const int sp = t2 & 3;
    const int sx = sp ^ ((srow >> 1) & 3);
    if constexpr (TERMS == 3) {
      if (half == 0) {
#pragma unroll
        for (int kt = 0; kt < 8; ++kt) {
          size_t off = (((size_t)(m0 + srow)) * 256 + (size_t)kt * 32 + (size_t)sx * 8) * 2;
          GLDS16((const char*)Ah + off, Xh + kt * 4096 + w4 * 1024);
        }
#pragma unroll
        for (int kt = 8; kt < 11; ++kt) {
          size_t off = (((size_t)(m0 + srow)) * 96 + (size_t)(kt - 8) * 32 + (size_t)sx * 8) * 2;
          GLDS16((const char*)Th + off, Xh + kt * 4096 + w4 * 1024);
        }
      } else {
#pragma unroll
        for (int kt = 0; kt < 8; ++kt) {
          size_t off = (((size_t)(m0 + srow)) * 256 + (size_t)kt * 32 + (size_t)sx * 8) * 2;
          GLDS16((const char*)Al + off, Xl + kt * 4096 + w4 * 1024);
        }
      }
    } else {
      if (half == 0) {
#pragma unroll
        for (int kt = 0; kt < 6; ++kt) {
          size_t off = (((size_t)(m0 + srow)) * 256 + (size_t)kt * 32 + (size_t)sx * 8) * 2;
          GLDS16((const char*)Ah + off, Xh + kt * 4096 + w4 * 1024);
        }
      } else {
#pragma unroll
        for (int kt = 6; kt < 8; ++kt) {
          size_t off = (((size_t)(m0 + srow)) * 256 + (size_t)kt * 32 + (size_t)sx * 8) * 2;
          GLDS16((const char*)Ah + off, Xh + kt * 4096 + w4 * 1024);
        }
#pragma unroll
        for (int kt = 8; kt < 11; ++kt) {
          size_t off = (((size_t)(m0 + srow)) * 96 + (size_t)(kt - 8) * 32 + (size_t)sx * 8) * 2;
          GLDS16((const char*)Th + off, Xh + kt * 4096 + w4 * 1024);
        }
      }
    }
  }
  asm volatile("s_waitcnt vmcnt(0)" ::: "memory");
  __syncthreads();

  int offA[2];
#pragma unroll
  for (int i = 0; i < 2; ++i) {
    int rowA = pg * 32 + i * 16 + lane15;
    offA[i] = rowA * 64 + ((g ^ ((rowA >> 1) & 3)) << 4);
  }

#pragma unroll 1
  for (int L = 0; L < 4; ++L) {
    if (L == 3 && cg >= 2) break;  // Wp cols 128..255 all-zero
    const __hip_bfloat16* WL = Wpk + (size_t)L * (11 * 16 * 2 * 512);

    f32x4 acc[2][4];
#pragma unroll
    for (int i = 0; i < 2; ++i)
#pragma unroll
      for (int j = 0; j < 4; ++j) acc[i][j] = (f32x4){0.f, 0.f, 0.f, 0.f};

    short8 a_h[2], a_l[2], b_h[2][4], b_l[2][4];

    auto loadB = [&](int buf, int kt) {
#pragma unroll
      for (int j = 0; j < 4; ++j) {
        const __hip_bfloat16* bp =
            WL + (((size_t)kt * 16 + (cg * 4 + j)) * 2) * 512 + (size_t)lane * 8;
        b_h[buf][j] = *(const short8*)bp;
        if constexpr (TERMS == 3) b_l[buf][j] = *(const short8*)(bp + 512);
      }
    };

    loadB(0, 0);

#pragma unroll
    for (int kt = 0; kt < 11; ++kt) {
      const int cb = kt & 1;
      if (kt < 10) loadB(cb ^ 1, kt + 1);  // B prefetch (global, long latency)
      // A direct from LDS (short latency; hidden by co-resident waves)
#pragma unroll
      for (int i = 0; i < 2; ++i) {
        a_h[i] = *(const short8*)(Xh + kt * 4096 + offA[i]);
        if constexpr (TERMS == 3) {
          if (kt < 8)
            a_l[i] = *(const short8*)(Xl + kt * 4096 + offA[i]);
          else
            a_l[i] = *(const short8*)((const char*)Tl +
                (((size_t)(m0 + pg * 32 + i * 16 + lane15)) * 96 +
                 (size_t)(kt - 8) * 32 + (size_t)g * 8) * 2);
        }
      }
      __builtin_amdgcn_s_setprio(1);
#pragma unroll
      for (int i = 0; i < 2; ++i)
#pragma unroll
        for (int j = 0; j < 4; ++j) {
          acc[i][j] = __builtin_amdgcn_mfma_f32_16x16x32_bf16(a_h[i], b_h[cb][j], acc[i][j], 0, 0, 0);
          if constexpr (TERMS == 3) {
            acc[i][j] = __builtin_amdgcn_mfma_f32_16x16x32_bf16(a_h[i], b_l[cb][j], acc[i][j], 0, 0, 0);
            acc[i][j] = __builtin_amdgcn_mfma_f32_16x16x32_bf16(a_l[i], b_h[cb][j], acc[i][j], 0, 0, 0);
          }
        }
      __builtin_amdgcn_s_setprio(0);
    }

    if (L < 3) {
      __syncthreads();  // all waves done READING X before overwrite
#pragma unroll
      for (int j = 0; j < 4; ++j) {
        int o = cg * 64 + j * 16 + lane15;
        float bv = bias_all[L * 256 + o];
        int kch = o >> 5;
        int s0 = (o >> 3) & 3;
        int e = o & 7;
#pragma unroll
        for (int i = 0; i < 2; ++i) {
          int mb = pg * 32 + i * 16 + g * 4;
#pragma unroll
          for (int r = 0; r < 4; ++r) {
            int m = mb + r;
            float v = fmaxf(acc[i][j][r] + bv, 0.f);
            __hip_bfloat16 h = __float2bfloat16(v);
            int boff = kch * 4096 + m * 64 + ((s0 ^ ((m >> 1) & 3)) << 4) + e * 2;
            *(__hip_bfloat16*)(Xh + boff) = h;
            if constexpr (TERMS == 3)
              *(__hip_bfloat16*)(Xl + boff) = __float2bfloat16(v - __bfloat162float(h));
          }
        }
      }
      __syncthreads();
    } else {
      // final layer: bias only, f32 out [rp][128] (col-groups 0,1 only)
#pragma unroll
      for (int j = 0; j < 4; ++j) {
        int o = cg * 64 + j * 16 + lane15;
        float bv = bias_all[768 + o];
#pragma unroll
        for (int i = 0; i < 2; ++i) {
          int mb = m0 + pg * 32 + i * 16 + g * 4;
#pragma unroll
          for (int r = 0; r < 4; ++r)
            PL[(size_t)(mb + r) * 128 + o] = acc[i][j][r] + bv;
        }
      }
    }
  }
}

// ---------------- scatter head outputs into ml ----------------
__global__ void scatter_kernel(const float* __restrict__ PL, const int* __restrict__ sel,
                               float* __restrict__ ml, int Nlev) {
  int t = blockIdx.x * 256 + threadIdx.x;
  if (t >= R_ * NPTS_ * K_) return;
  int k = t % K_;
  int rp = t / K_;
  int i = sel[rp];
  int r = rp / NPTS_;
  ml[((size_t)r * K_ + k) * Nlev + i] = PL[(size_t)rp * 128 + k];
}

extern "C" void kernel_launch(void* const* d_in, const int* in_sizes, int n_in,
                              void* d_out, int out_size, void* d_ws, size_t ws_size,
                              hipStream_t stream) {
  (void)in_sizes; (void)n_in; (void)out_size; (void)ws_size;
  const float* feat = (const float*)d_in[0];
  const float* bboxes = (const float*)d_in[1];
  const int* labels = (const int*)d_in[2];
  const float* coarse = (const float*)d_in[3];
  const float* W1 = (const float*)d_in[4];
  const float* b1 = (const float*)d_in[5];
  const float* W2 = (const float*)d_in[6];
  const float* b2 = (const float*)d_in[7];
  const float* W3 = (const float*)d_in[8];
  const float* b3 = (const float*)d_in[9];
  const float* Wp = (const float*)d_in[10];
  const float* bp = (const float*)d_in[11];
  float* out = (float*)d_out;

  char* p = (char*)d_ws;
  auto alloc = [&](size_t bytes) { char* r = p; p += (bytes + 255) & ~(size_t)255; return r; };
  float* featT = (float*)alloc(16777216ull * 4);
  float* coarseT = (float*)alloc(254016ull * 4);
  float* ml14 = (float*)alloc(1016064ull * 4);
  float* ml28 = (float*)alloc(4064256ull * 4);
  float* ml56 = (float*)alloc(16257024ull * 4);
  float* PL = (float*)alloc(6422528ull * 4);
  int* sel = (int*)alloc(50176ull * 4);
  __hip_bfloat16* Xa_h = (__hip_bfloat16*)alloc(12845056ull * 2);
  __hip_bfloat16* Xa_l = (__hip_bfloat16*)alloc(12845056ull * 2);
  __hip_bfloat16* Ct_h = (__hip_bfloat16*)alloc(4816896ull * 2);
  __hip_bfloat16* Ct_l = (__hip_bfloat16*)alloc(4816896ull * 2);
  __hip_bfloat16* Wpk = (__hip_bfloat16*)alloc(720896ull * 2);  // 4*11*16*2*64*8
  float* bias_all = (float*)alloc(1024ull * 4);

  const int N = R_ * NPTS_;  // 50176
  const int B = R_ * K_;     // 5184

  transpose_feat_kernel<<<dim3(8, 8, 256), dim3(32, 8), 0, stream>>>(feat, featT);
  transpose_coarse_kernel<<<3969, 256, 0, stream>>>(coarse, coarseT);
  prep_wpack_kernel<<<357, 256, 0, stream>>>(W1, W2, W3, Wp, b1, b2, b3, bp, Wpk, bias_all);

  // step 0: 7 -> 14 (no refine)
  upsample2x_kernel<<<dim3(1, 4, B), dim3(64, 2), 0, stream>>>(coarse, ml14, 7, 7);

  // ---- step 1: 14 -> 28, refine ALL 784 points (exact 3-term head) ----
  upsample2x_kernel<<<dim3(1, 7, B), dim3(64, 2), 0, stream>>>(ml14, ml28, 14, 14);
  iota_kernel<<<196, 256, 0, stream>>>(sel);
  sample_kernel<<<N, 256, 0, stream>>>(sel, bboxes, featT, coarseT, Xa_h, Xa_l, Ct_h, Ct_l, 28, 28);
  fused_head_kernel<3><<<784, 512, 0, stream>>>(Xa_h, Xa_l, Ct_h, Ct_l, Wpk, bias_all, PL);
  scatter_kernel<<<15876, 256, 0, stream>>>(PL, sel, ml28, 784);

  // ---- step 2: 28 -> 56, refine top-784 of 3136 (exact 3-term head) ----
  upsample2x_kernel<<<dim3(1, 14, B), dim3(64, 2), 0, stream>>>(ml28, ml56, 28, 28);
  topk_kernel<<<R_, 256, 0, stream>>>(ml56, labels, 3136, sel);
  sample_kernel<<<N, 256, 0, stream>>>(sel, bboxes, featT, coarseT, Xa_h, Xa_l, Ct_h, Ct_l, 56, 56);
  fused_head_kernel<3><<<784, 512, 0, stream>>>(Xa_h, Xa_l, Ct_h, Ct_l, Wpk, bias_all, PL);
  scatter_kernel<<<15876, 256, 0, stream>>>(PL, sel, ml56, 3136);

  // ---- step 3: 56 -> 112 (into d_out), refine top-784 of 12544 (1-term bf16 head) ----
  upsample2x_kernel<<<dim3(1, 28, B), dim3(64, 2), 0, stream>>>(ml56, out, 56, 56);
  topk_kernel<<<R_, 256, 0, stream>>>(out, labels, 12544, sel);
  sample_kernel<<<N, 256, 0, stream>>>(sel, bboxes, featT, coarseT, Xa_h, Xa_l, Ct_h, Ct_l, 112, 112);
  fused_head_kernel<1><<<784, 512, 0, stream>>>(Xa_h, nullptr, Ct_h, nullptr, Wpk, bias_all, PL);
  scatter_kernel<<<15876, 256, 0, stream>>>(PL, sel, out, 12544);
}

// Round 11
// 912.321 us; speedup vs baseline: 1.0593x; 1.0015x over previous
//
#include <hip/hip_runtime.h>
#include <hip/hip_bf16.h>
#include <cstdint>
#include <cstddef>

#define R_ 64
#define K_ 81
#define NPTS_ 784

typedef __attribute__((ext_vector_type(8))) short short8;
typedef __attribute__((ext_vector_type(4))) float f32x4;

#define GLDS16(G, L)                                                           \
  __builtin_amdgcn_global_load_lds(                                            \
      (__attribute__((address_space(1))) void*)(void*)(G),                     \
      (__attribute__((address_space(3))) void*)(L), 16, 0, 0)

// ---------------- transpose feat [C][H][W] -> [H][W][C] ----------------
__global__ __launch_bounds__(256) void transpose_feat_kernel(const float* __restrict__ in,
                                                             float* __restrict__ out) {
  __shared__ float tile[32][33];
  int y = blockIdx.z;
  int x0 = blockIdx.x * 32, c0 = blockIdx.y * 32;
  int tx = threadIdx.x, ty = threadIdx.y;
#pragma unroll
  for (int j = 0; j < 32; j += 8)
    tile[ty + j][tx] = in[(size_t)(c0 + ty + j) * 65536 + (size_t)y * 256 + x0 + tx];
  __syncthreads();
#pragma unroll
  for (int j = 0; j < 32; j += 8)
    out[((size_t)y * 256 + (x0 + ty + j)) * 256 + c0 + tx] = tile[tx][ty + j];
}

// ---------------- transpose coarse [R][K][49] -> [R][49][K] ----------------
__global__ void transpose_coarse_kernel(const float* __restrict__ in, float* __restrict__ out) {
  int t = blockIdx.x * 256 + threadIdx.x;
  if (t >= R_ * 49 * K_) return;
  int k = t % K_;
  int t2 = t / K_;
  int pos = t2 % 49;
  int r = t2 / 49;
  out[t] = in[((size_t)r * K_ + k) * 49 + pos];
}

// ---------------- pack W into MFMA-fragment-linear layout (hi/lo bf16) ----------------
__global__ void prep_wpack_kernel(const float* __restrict__ W1, const float* __restrict__ W2,
                                  const float* __restrict__ W3, const float* __restrict__ Wp,
                                  const float* __restrict__ b1, const float* __restrict__ b2,
                                  const float* __restrict__ b3, const float* __restrict__ bp,
                                  __hip_bfloat16* __restrict__ Wpk, float* __restrict__ bias_all) {
  int t = blockIdx.x * 256 + threadIdx.x;
  if (t < 90112) {
    int lane = t & 63;
    int t2 = t >> 6;
    int hl = t2 & 1;
    t2 >>= 1;
    int jg = t2 & 15;
    t2 >>= 4;
    int kt = t2 % 11;
    int L = t2 / 11;
    int o = jg * 16 + (lane & 15);
    int kbase = kt * 32 + (lane >> 4) * 8;
    const float* Wsrc = (L == 0) ? W1 : (L == 1) ? W2 : (L == 2) ? W3 : Wp;
    int Omax = (L == 3) ? 81 : 256;
    __hip_bfloat16 outv[8];
#pragma unroll
    for (int e = 0; e < 8; ++e) {
      int k = kbase + e;
      float v = (o < Omax && k < 337) ? Wsrc[o * 337 + k] : 0.f;
      __hip_bfloat16 h = __float2bfloat16(v);
      outv[e] = hl ? __float2bfloat16(v - __bfloat162float(h)) : h;
    }
    *(short8*)(Wpk + (size_t)t * 8) = *(const short8*)outv;
  } else if (t < 90112 + 1024) {
    int k = t - 90112;
    float v = 0.f;
    if (k < 256) v = b1[k];
    else if (k < 512) v = b2[k - 256];
    else if (k < 768) v = b3[k - 512];
    else if (k < 768 + 81) v = bp[k - 768];
    bias_all[k] = v;
  }
}

// ---------------- 2x bilinear upsample, quad form ----------------
__global__ __launch_bounds__(128) void upsample2x_kernel(const float* __restrict__ in,
                                                         float* __restrict__ out,
                                                         int Hin, int Win) {
  int b = blockIdx.z;
  int iy = blockIdx.y * 2 + threadIdx.y;
  int ix = blockIdx.x * 64 + threadIdx.x;
  if (ix >= Win || iy >= Hin) return;
  const float* p = in + (size_t)b * Hin * Win;
  int rT = (iy == 0) ? 0 : iy - 1;
  int rB = (iy == Hin - 1) ? iy : iy + 1;
  int cL = (ix == 0) ? 0 : ix - 1;
  int cR = (ix == Win - 1) ? ix : ix + 1;
  float wyT1 = (iy == 0) ? 0.f : 0.75f;
  float wyB1 = (iy == Hin - 1) ? 0.f : 0.25f;
  float wxE1 = (ix == 0) ? 0.f : 0.75f;
  float wxO1 = (ix == Win - 1) ? 0.f : 0.25f;
  float wyT0 = 1.f - wyT1, wyB0 = 1.f - wyB1;
  float wxE0 = 1.f - wxE1, wxO0 = 1.f - wxO1;

  const float* rowA = p + (size_t)rT * Win;
  const float* rowM = p + (size_t)iy * Win;
  const float* rowC = p + (size_t)rB * Win;
  float al = rowA[cL], am = rowA[ix], ar = rowA[cR];
  float mL = rowM[cL], mm = rowM[ix], mr = rowM[cR];
  float cl = rowC[cL], cm = rowC[ix], cr = rowC[cR];

  float aE = wxE0 * al + wxE1 * am;
  float aO = wxO0 * am + wxO1 * ar;
  float mE = wxE0 * mL + wxE1 * mm;
  float mO = wxO0 * mm + wxO1 * mr;
  float cE = wxE0 * cl + wxE1 * cm;
  float cO = wxO0 * cm + wxO1 * cr;

  float oTE = wyT0 * aE + wyT1 * mE;
  float oTO = wyT0 * aO + wyT1 * mO;
  float oBE = wyB0 * mE + wyB1 * cE;
  float oBO = wyB0 * mO + wyB1 * cO;

  int Wout = 2 * Win;
  float* ob = out + ((size_t)b * (2 * Hin) + 2 * iy) * Wout + 2 * ix;
  *(float2*)ob = make_float2(oTE, oTO);
  *(float2*)(ob + Wout) = make_float2(oBE, oBO);
}

// ---------------- iota selection (step 1: all 784 points) ----------------
__global__ void iota_kernel(int* __restrict__ sel) {
  int t = blockIdx.x * 256 + threadIdx.x;
  if (t < R_ * NPTS_) sel[t] = t % NPTS_;
}

// ---------------- per-ROI top-784 smallest |gt| (jax top_k tie semantics) ----------------
__global__ __launch_bounds__(256) void topk_kernel(const float* __restrict__ ml,
                                                   const int* __restrict__ labels,
                                                   int N, int* __restrict__ sel) {
  int r = blockIdx.x;
  const float* gt = ml + ((size_t)r * K_ + (labels[r] + 1)) * N;
  __shared__ unsigned int hist[256];
  __shared__ unsigned int sh_prefix, sh_remaining, sh_countless;
  int tid = threadIdx.x;

  unsigned int prefix = 0;
  unsigned int remaining = NPTS_;
  unsigned int count_less = 0;
  for (int pass = 0; pass < 4; ++pass) {
    int shift = 24 - 8 * pass;
    hist[tid] = 0;
    __syncthreads();
    for (int i = tid; i < N; i += 256) {
      unsigned int v = __float_as_uint(fabsf(gt[i]));
      bool match = (pass == 0) || ((v >> (shift + 8)) == prefix);
      if (match) atomicAdd(&hist[(v >> shift) & 255u], 1u);
    }
    __syncthreads();
    if (tid == 0) {
      unsigned int cum = 0, before = 0;
      int d = 255;
      for (int dd = 0; dd < 256; ++dd) {
        unsigned int c = hist[dd];
        if (cum + c >= remaining) { before = cum; d = dd; break; }
        cum += c;
      }
      sh_prefix = (prefix << 8) | (unsigned int)d;
      sh_remaining = remaining - before;
      sh_countless = count_less + before;
    }
    __syncthreads();
    prefix = sh_prefix;
    remaining = sh_remaining;
    count_less = sh_countless;
    __syncthreads();
  }
  unsigned int vstar = prefix;
  unsigned int need_eq = NPTS_ - count_less;

  __shared__ unsigned int wtot_less[4], wtot_eq[4];
  unsigned int base_less = 0, base_eq = 0;
  int lane = tid & 63, wv = tid >> 6;
  int* selr = sel + (size_t)r * NPTS_;
  for (int base = 0; base < N; base += 256) {
    int i = base + tid;
    bool less = false, eq = false;
    if (i < N) {
      unsigned int v = __float_as_uint(fabsf(gt[i]));
      less = v < vstar;
      eq = v == vstar;
    }
    unsigned long long ml_ = __ballot(less);
    unsigned long long me_ = __ballot(eq);
    unsigned long long lanemask = (lane == 0) ? 0ull : ((~0ull) >> (64 - lane));
    unsigned int pl = __popcll(ml_ & lanemask);
    unsigned int pe = __popcll(me_ & lanemask);
    if (lane == 0) { wtot_less[wv] = (unsigned int)__popcll(ml_); wtot_eq[wv] = (unsigned int)__popcll(me_); }
    __syncthreads();
    unsigned int off_l = 0, off_e = 0, tot_l = 0, tot_e = 0;
#pragma unroll
    for (int w2 = 0; w2 < 4; ++w2) {
      unsigned int tl = wtot_less[w2], te = wtot_eq[w2];
      if (w2 < wv) { off_l += tl; off_e += te; }
      tot_l += tl;
      tot_e += te;
    }
    if (less) selr[base_less + off_l + pl] = i;
    if (eq) {
      unsigned int er = base_eq + off_e + pe;
      if (er < need_eq) selr[count_less + er] = i;
    }
    base_less += tot_l;
    base_eq += tot_e;
    __syncthreads();
  }
}

// ---------------- sample fine + coarse; write hi/lo bf16 splits ----------------
__global__ __launch_bounds__(256) void sample_kernel(const int* __restrict__ sel,
                                                     const float* __restrict__ bboxes,
                                                     const float* __restrict__ featT,
                                                     const float* __restrict__ coarseT,
                                                     __hip_bfloat16* __restrict__ Xh,
                                                     __hip_bfloat16* __restrict__ Xl,
                                                     __hip_bfloat16* __restrict__ Cth,
                                                     __hip_bfloat16* __restrict__ Ctl,
                                                     int Wlev, int Hlev) {
  int rp = blockIdx.x;
  int r = rp / NPTS_;
  int idx = sel[rp];
  int tid = threadIdx.x;

  float px = ((float)(idx % Wlev) + 0.5f) / (float)Wlev;
  float py = ((float)(idx / Wlev) + 0.5f) / (float)Hlev;
  float bx0 = bboxes[r * 4 + 0], by0 = bboxes[r * 4 + 1];
  float bw = __fsub_rn(bboxes[r * 4 + 2], bx0);
  float bh = __fsub_rn(bboxes[r * 4 + 3], by0);
  float cx = __fadd_rn(bx0, __fmul_rn(px, bw));
  float cy = __fadd_rn(by0, __fmul_rn(py, bh));

  {
    float gx = __fsub_rn(__fmul_rn(cx, 0.25f), 0.5f);
    float gy = __fsub_rn(__fmul_rn(cy, 0.25f), 0.5f);
    float fxf = floorf(gx), fyf = floorf(gy);
    float fx = __fsub_rn(gx, fxf), fy = __fsub_rn(gy, fyf);
    int x0 = (int)fxf, y0 = (int)fyf;
    float ofx = __fsub_rn(1.f, fx), ofy = __fsub_rn(1.f, fy);
    float w00 = __fmul_rn(ofx, ofy);
    float w10 = __fmul_rn(fx, ofy);
    float w01 = __fmul_rn(ofx, fy);
    float w11 = __fmul_rn(fx, fy);
    bool vx0 = (x0 >= 0) && (x0 < 256), vx1 = (x0 + 1 >= 0) && (x0 + 1 < 256);
    bool vy0 = (y0 >= 0) && (y0 < 256), vy1 = (y0 + 1 >= 0) && (y0 + 1 < 256);
    float W00 = (vx0 && vy0) ? w00 : 0.f;
    float W10 = (vx1 && vy0) ? w10 : 0.f;
    float W01 = (vx0 && vy1) ? w01 : 0.f;
    float W11 = (vx1 && vy1) ? w11 : 0.f;
    int x0c = min(max(x0, 0), 255), x1c = min(max(x0 + 1, 0), 255);
    int y0c = min(max(y0, 0), 255), y1c = min(max(y0 + 1, 0), 255);
    const float* p00 = featT + ((size_t)(y0c * 256 + x0c)) * 256;
    const float* p10 = featT + ((size_t)(y0c * 256 + x1c)) * 256;
    const float* p01 = featT + ((size_t)(y1c * 256 + x0c)) * 256;
    const float* p11 = featT + ((size_t)(y1c * 256 + x1c)) * 256;
    float acc = __fmul_rn(p00[tid], W00);
    acc = __fadd_rn(acc, __fmul_rn(p10[tid], W10));
    acc = __fadd_rn(acc, __fmul_rn(p01[tid], W01));
    acc = __fadd_rn(acc, __fmul_rn(p11[tid], W11));
    __hip_bfloat16 h = __float2bfloat16(acc);
    Xh[(size_t)rp * 256 + tid] = h;
    Xl[(size_t)rp * 256 + tid] = __float2bfloat16(acc - __bfloat162float(h));
  }

  if (tid < 96) {
    float acc = 0.f;
    if (tid < K_) {
      float gx = __fsub_rn(__fmul_rn(px, 7.f), 0.5f);
      float gy = __fsub_rn(__fmul_rn(py, 7.f), 0.5f);
      float fxf = floorf(gx), fyf = floorf(gy);
      float fx = __fsub_rn(gx, fxf), fy = __fsub_rn(gy, fyf);
      int x0 = (int)fxf, y0 = (int)fyf;
      float ofx = __fsub_rn(1.f, fx), ofy = __fsub_rn(1.f, fy);
      float w00 = __fmul_rn(ofx, ofy);
      float w10 = __fmul_rn(fx, ofy);
      float w01 = __fmul_rn(ofx, fy);
      float w11 = __fmul_rn(fx, fy);
      bool vx0 = (x0 >= 0) && (x0 < 7), vx1 = (x0 + 1 >= 0) && (x0 + 1 < 7);
      bool vy0 = (y0 >= 0) && (y0 < 7), vy1 = (y0 + 1 >= 0) && (y0 + 1 < 7);
      float W00 = (vx0 && vy0) ? w00 : 0.f;
      float W10 = (vx1 && vy0) ? w10 : 0.f;
      float W01 = (vx0 && vy1) ? w01 : 0.f;
      float W11 = (vx1 && vy1) ? w11 : 0.f;
      int x0c = min(max(x0, 0), 6), x1c = min(max(x0 + 1, 0), 6);
      int y0c = min(max(y0, 0), 6), y1c = min(max(y0 + 1, 0), 6);
      const float* cb = coarseT + (size_t)r * 49 * K_;
      acc = __fmul_rn(cb[(size_t)(y0c * 7 + x0c) * K_ + tid], W00);
      acc = __fadd_rn(acc, __fmul_rn(cb[(size_t)(y0c * 7 + x1c) * K_ + tid], W10));
      acc = __fadd_rn(acc, __fmul_rn(cb[(size_t)(y1c * 7 + x0c) * K_ + tid], W01));
      acc = __fadd_rn(acc, __fmul_rn(cb[(size_t)(y1c * 7 + x1c) * K_ + tid], W11));
    }
    __hip_bfloat16 h = __float2bfloat16(acc);
    Cth[(size_t)rp * 96 + tid] = h;
    Ctl[(size_t)rp * 96 + tid] = __float2bfloat16(acc - __bfloat162float(h));
  }
}

// ---------------- FUSED 4-layer point head, v6: 4 waves x (64 pts x 64 cols) ----------------
// Halves per-wave B bytes per FLOP vs v5 (L1-BW was the bottleneck: model 23% == measured
// ~20% MfmaUtil). Register plan that FITS (unlike R7's ~200): acc 4x4 (64) + B ping-pong
// (64) + A read per-chunk direct from LDS, no ping-pong (32) ~ 180 < 256 cap.
// sched_barrier(0) after B prefetch stops the compiler sinking the loads (R7 failure).
template <int TERMS>
__global__ __launch_bounds__(256, 2) void fused_head_kernel(
    const __hip_bfloat16* __restrict__ Ah, const __hip_bfloat16* __restrict__ Al,
    const __hip_bfloat16* __restrict__ Th, const __hip_bfloat16* __restrict__ Tl,
    const __hip_bfloat16* __restrict__ Wpk,
    const float* __restrict__ bias_all, float* __restrict__ PL) {
  constexpr int XPLANE = 11 * 4096;  // 45056 B (hi)
  constexpr int XLO = 8 * 4096;      // 32768 B (lo, activation chunks only)
  __shared__ char lds[(TERMS == 3) ? XPLANE + XLO : XPLANE];
  char* Xh = lds;
  char* Xl = lds + XPLANE;  // chunks 0..7 only; TERMS==3

  const int tid = threadIdx.x;
  const int lane = tid & 63;
  const int w = tid >> 6;
  const int g = lane >> 4;
  const int lane15 = lane & 15;
  const int m0 = blockIdx.x * 64;

  // ---- stage X once (pre-swizzled global source, linear LDS dest) ----
  {
    const int srow = tid >> 2;
    const int sp = tid & 3;
    const int sx = sp ^ ((srow >> 1) & 3);
#pragma unroll
    for (int kt = 0; kt < 8; ++kt) {
      size_t off = (((size_t)(m0 + srow)) * 256 + (size_t)kt * 32 + (size_t)sx * 8) * 2;
      GLDS16((const char*)Ah + off, Xh + kt * 4096 + w * 1024);
      if constexpr (TERMS == 3) GLDS16((const char*)Al + off, Xl + kt * 4096 + w * 1024);
    }
#pragma unroll
    for (int kt = 8; kt < 11; ++kt) {
      size_t off = (((size_t)(m0 + srow)) * 96 + (size_t)(kt - 8) * 32 + (size_t)sx * 8) * 2;
      GLDS16((const char*)Th + off, Xh + kt * 4096 + w * 1024);
    }
  }
  asm volatile("s_waitcnt vmcnt(0)" ::: "memory");
  __syncthreads();

  int offA[4];
#pragma unroll
  for (int i = 0; i < 4; ++i) {
    int rowA = i * 16 + lane15;
    offA[i] = rowA * 64 + ((g ^ ((rowA >> 1) & 3)) << 4);
  }

#pragma unroll 1
  for (int L = 0; L < 4; ++L) {
    if (L == 3 && w >= 2) break;  // Wp cols 128..255 all-zero
    const __hip_bfloat16* WL = Wpk + (size_t)L * (11 * 16 * 2 * 512);

    f32x4 acc[4][4];
#pragma unroll
    for (int i = 0; i < 4; ++i)
#pragma unroll
      for (int j = 0; j < 4; ++j) acc[i][j] = (f32x4){0.f, 0.f, 0.f, 0.f};

    short8 a_h[4], a_l[4], b_h[2][4], b_l[2][4];

    auto loadB = [&](int buf, int kt) {
#pragma unroll
      for (int j = 0; j < 4; ++j) {
        const __hip_bfloat16* bp =
            WL + (((size_t)kt * 16 + (w * 4 + j)) * 2) * 512 + (size_t)lane * 8;
        b_h[buf][j] = *(const short8*)bp;
        if constexpr (TERMS == 3) b_l[buf][j] = *(const short8*)(bp + 512);
      }
    };

    loadB(0, 0);

#pragma unroll
    for (int kt = 0; kt < 11; ++kt) {
      const int cb = kt & 1;
      if (kt < 10) loadB(cb ^ 1, kt + 1);  // B prefetch (global, long latency)
      __builtin_amdgcn_sched_barrier(0);   // pin: prefetch issues BEFORE the MFMA cluster
      // A direct from LDS (short latency; hidden by co-resident wave)
#pragma unroll
      for (int i = 0; i < 4; ++i) {
        a_h[i] = *(const short8*)(Xh + kt * 4096 + offA[i]);
        if constexpr (TERMS == 3) {
          if (kt < 8)
            a_l[i] = *(const short8*)(Xl + kt * 4096 + offA[i]);
          else
            a_l[i] = *(const short8*)((const char*)Tl +
                (((size_t)(m0 + i * 16 + lane15)) * 96 + (size_t)(kt - 8) * 32 +
                 (size_t)g * 8) * 2);
        }
      }
      __builtin_amdgcn_s_setprio(1);
#pragma unroll
      for (int i = 0; i < 4; ++i)
#pragma unroll
        for (int j = 0; j < 4; ++j) {
          acc[i][j] = __builtin_amdgcn_mfma_f32_16x16x32_bf16(a_h[i], b_h[cb][j], acc[i][j], 0, 0, 0);
          if constexpr (TERMS == 3) {
            acc[i][j] = __builtin_amdgcn_mfma_f32_16x16x32_bf16(a_h[i], b_l[cb][j], acc[i][j], 0, 0, 0);
            acc[i][j] = __builtin_amdgcn_mfma_f32_16x16x32_bf16(a_l[i], b_h[cb][j], acc[i][j], 0, 0, 0);
          }
        }
      __builtin_amdgcn_s_setprio(0);
    }

    if (L < 3) {
      __syncthreads();  // all waves done READING X before overwrite
#pragma unroll
      for (int j = 0; j < 4; ++j) {
        int o = w * 64 + j * 16 + lane15;
        float bv = bias_all[L * 256 + o];
        int kch = o >> 5;
        int s0 = (o >> 3) & 3;
        int e = o & 7;
#pragma unroll
        for (int i = 0; i < 4; ++i) {
          int mb = i * 16 + g * 4;
#pragma unroll
          for (int r = 0; r < 4; ++r) {
            int m = mb + r;
            float v = fmaxf(acc[i][j][r] + bv, 0.f);
            __hip_bfloat16 h = __float2bfloat16(v);
            int boff = kch * 4096 + m * 64 + ((s0 ^ ((m >> 1) & 3)) << 4) + e * 2;
            *(__hip_bfloat16*)(Xh + boff) = h;
            if constexpr (TERMS == 3)
              *(__hip_bfloat16*)(Xl + boff) = __float2bfloat16(v - __bfloat162float(h));
          }
        }
      }
      __syncthreads();
    } else {
      // final layer: bias only, f32 out [rp][128] (waves 0,1 only)
#pragma unroll
      for (int j = 0; j < 4; ++j) {
        int o = w * 64 + j * 16 + lane15;
        float bv = bias_all[768 + o];
#pragma unroll
        for (int i = 0; i < 4; ++i) {
          int mb = i * 16 + g * 4;
#pragma unroll
          for (int r = 0; r < 4; ++r)
            PL[(size_t)(m0 + mb + r) * 128 + o] = acc[i][j][r] + bv;
        }
      }
    }
  }
}

// ---------------- scatter head outputs into ml ----------------
__global__ void scatter_kernel(const float* __restrict__ PL, const int* __restrict__ sel,
                               float* __restrict__ ml, int Nlev) {
  int t = blockIdx.x * 256 + threadIdx.x;
  if (t >= R_ * NPTS_ * K_) return;
  int k = t % K_;
  int rp = t / K_;
  int i = sel[rp];
  int r = rp / NPTS_;
  ml[((size_t)r * K_ + k) * Nlev + i] = PL[(size_t)rp * 128 + k];
}

extern "C" void kernel_launch(void* const* d_in, const int* in_sizes, int n_in,
                              void* d_out, int out_size, void* d_ws, size_t ws_size,
                              hipStream_t stream) {
  (void)in_sizes; (void)n_in; (void)out_size; (void)ws_size;
  const float* feat = (const float*)d_in[0];
  const float* bboxes = (const float*)d_in[1];
  const int* labels = (const int*)d_in[2];
  const float* coarse = (const float*)d_in[3];
  const float* W1 = (const float*)d_in[4];
  const float* b1 = (const float*)d_in[5];
  const float* W2 = (const float*)d_in[6];
  const float* b2 = (const float*)d_in[7];
  const float* W3 = (const float*)d_in[8];
  const float* b3 = (const float*)d_in[9];
  const float* Wp = (const float*)d_in[10];
  const float* bp = (const float*)d_in[11];
  float* out = (float*)d_out;

  char* p = (char*)d_ws;
  auto alloc = [&](size_t bytes) { char* r = p; p += (bytes + 255) & ~(size_t)255; return r; };
  float* featT = (float*)alloc(16777216ull * 4);
  float* coarseT = (float*)alloc(254016ull * 4);
  float* ml14 = (float*)alloc(1016064ull * 4);
  float* ml28 = (float*)alloc(4064256ull * 4);
  float* ml56 = (float*)alloc(16257024ull * 4);
  float* PL = (float*)alloc(6422528ull * 4);
  int* sel = (int*)alloc(50176ull * 4);
  __hip_bfloat16* Xa_h = (__hip_bfloat16*)alloc(12845056ull * 2);
  __hip_bfloat16* Xa_l = (__hip_bfloat16*)alloc(12845056ull * 2);
  __hip_bfloat16* Ct_h = (__hip_bfloat16*)alloc(4816896ull * 2);
  __hip_bfloat16* Ct_l = (__hip_bfloat16*)alloc(4816896ull * 2);
  __hip_bfloat16* Wpk = (__hip_bfloat16*)alloc(720896ull * 2);  // 4*11*16*2*64*8
  float* bias_all = (float*)alloc(1024ull * 4);

  const int N = R_ * NPTS_;  // 50176
  const int B = R_ * K_;     // 5184

  transpose_feat_kernel<<<dim3(8, 8, 256), dim3(32, 8), 0, stream>>>(feat, featT);
  transpose_coarse_kernel<<<3969, 256, 0, stream>>>(coarse, coarseT);
  prep_wpack_kernel<<<357, 256, 0, stream>>>(W1, W2, W3, Wp, b1, b2, b3, bp, Wpk, bias_all);

  // step 0: 7 -> 14 (no refine)
  upsample2x_kernel<<<dim3(1, 4, B), dim3(64, 2), 0, stream>>>(coarse, ml14, 7, 7);

  // ---- step 1: 14 -> 28, refine ALL 784 points (exact 3-term head) ----
  upsample2x_kernel<<<dim3(1, 7, B), dim3(64, 2), 0, stream>>>(ml14, ml28, 14, 14);
  iota_kernel<<<196, 256, 0, stream>>>(sel);
  sample_kernel<<<N, 256, 0, stream>>>(sel, bboxes, featT, coarseT, Xa_h, Xa_l, Ct_h, Ct_l, 28, 28);
  fused_head_kernel<3><<<784, 256, 0, stream>>>(Xa_h, Xa_l, Ct_h, Ct_l, Wpk, bias_all, PL);
  scatter_kernel<<<15876, 256, 0, stream>>>(PL, sel, ml28, 784);

  // ---- step 2: 28 -> 56, refine top-784 of 3136 (exact 3-term head) ----
  upsample2x_kernel<<<dim3(1, 14, B), dim3(64, 2), 0, stream>>>(ml28, ml56, 28, 28);
  topk_kernel<<<R_, 256, 0, stream>>>(ml56, labels, 3136, sel);
  sample_kernel<<<N, 256, 0, stream>>>(sel, bboxes, featT, coarseT, Xa_h, Xa_l, Ct_h, Ct_l, 56, 56);
  fused_head_kernel<3><<<784, 256, 0, stream>>>(Xa_h, Xa_l, Ct_h, Ct_l, Wpk, bias_all, PL);
  scatter_kernel<<<15876, 256, 0, stream>>>(PL, sel, ml56, 3136);

  // ---- step 3: 56 -> 112 (into d_out), refine top-784 of 12544 (1-term bf16 head) ----
  upsample2x_kernel<<<dim3(1, 28, B), dim3(64, 2), 0, stream>>>(ml56, out, 56, 56);
  topk_kernel<<<R_, 256, 0, stream>>>(out, labels, 12544, sel);
  sample_kernel<<<N, 256, 0, stream>>>(sel, bboxes, featT, coarseT, Xa_h, Xa_l, Ct_h, Ct_l, 112, 112);
  fused_head_kernel<1><<<784, 256, 0, stream>>>(Xa_h, nullptr, Ct_h, nullptr, Wpk, bias_all, PL);
  scatter_kernel<<<15876, 256, 0, stream>>>(PL, sel, out, 12544);
}

// Round 12
// 831.442 us; speedup vs baseline: 1.1623x; 1.0973x over previous
//
#include <hip/hip_runtime.h>
#include <hip/hip_bf16.h>
#include <cstdint>
#include <cstddef>

#define R_ 64
#define K_ 81
#define NPTS_ 784

typedef __attribute__((ext_vector_type(8))) short short8;
typedef __attribute__((ext_vector_type(4))) float f32x4;

#define GLDS16(G, L)                                                           \
  __builtin_amdgcn_global_load_lds(                                            \
      (__attribute__((address_space(1))) void*)(void*)(G),                     \
      (__attribute__((address_space(3))) void*)(L), 16, 0, 0)

// ---------------- transpose feat [C][H][W] -> [H][W][C] ----------------
__global__ __launch_bounds__(256) void transpose_feat_kernel(const float* __restrict__ in,
                                                             float* __restrict__ out) {
  __shared__ float tile[32][33];
  int y = blockIdx.z;
  int x0 = blockIdx.x * 32, c0 = blockIdx.y * 32;
  int tx = threadIdx.x, ty = threadIdx.y;
#pragma unroll
  for (int j = 0; j < 32; j += 8)
    tile[ty + j][tx] = in[(size_t)(c0 + ty + j) * 65536 + (size_t)y * 256 + x0 + tx];
  __syncthreads();
#pragma unroll
  for (int j = 0; j < 32; j += 8)
    out[((size_t)y * 256 + (x0 + ty + j)) * 256 + c0 + tx] = tile[tx][ty + j];
}

// ---------------- merged prep: W pack (hi/lo) + bias pack + coarse transpose ----------------
// Wpk index: ((((L*11 + kt)*16 + jtile)*2 + hl)*64 + lane)*8
__global__ void prep_all_kernel(const float* __restrict__ W1, const float* __restrict__ W2,
                                const float* __restrict__ W3, const float* __restrict__ Wp,
                                const float* __restrict__ b1, const float* __restrict__ b2,
                                const float* __restrict__ b3, const float* __restrict__ bp,
                                const float* __restrict__ coarse_in,
                                __hip_bfloat16* __restrict__ Wpk, float* __restrict__ bias_all,
                                float* __restrict__ coarseT) {
  int t = blockIdx.x * 256 + threadIdx.x;
  if (t < 90112) {
    int lane = t & 63;
    int t2 = t >> 6;
    int hl = t2 & 1;
    t2 >>= 1;
    int jg = t2 & 15;
    t2 >>= 4;
    int kt = t2 % 11;
    int L = t2 / 11;
    int o = jg * 16 + (lane & 15);
    int kbase = kt * 32 + (lane >> 4) * 8;
    const float* Wsrc = (L == 0) ? W1 : (L == 1) ? W2 : (L == 2) ? W3 : Wp;
    int Omax = (L == 3) ? 81 : 256;
    __hip_bfloat16 outv[8];
#pragma unroll
    for (int e = 0; e < 8; ++e) {
      int k = kbase + e;
      float v = (o < Omax && k < 337) ? Wsrc[o * 337 + k] : 0.f;
      __hip_bfloat16 h = __float2bfloat16(v);
      outv[e] = hl ? __float2bfloat16(v - __bfloat162float(h)) : h;
    }
    *(short8*)(Wpk + (size_t)t * 8) = *(const short8*)outv;
  } else if (t < 90112 + 1024) {
    int k = t - 90112;
    float v = 0.f;
    if (k < 256) v = b1[k];
    else if (k < 512) v = b2[k - 256];
    else if (k < 768) v = b3[k - 512];
    else if (k < 768 + 81) v = bp[k - 768];
    bias_all[k] = v;
  } else {
    int t2 = t - 91136;
    if (t2 < R_ * 49 * K_) {
      int k = t2 % K_;
      int t3 = t2 / K_;
      int pos = t3 % 49;
      int r = t3 / 49;
      coarseT[t2] = coarse_in[((size_t)r * K_ + k) * 49 + pos];
    }
  }
}

// ---------------- 2x bilinear upsample, quad form ----------------
__global__ __launch_bounds__(128) void upsample2x_kernel(const float* __restrict__ in,
                                                         float* __restrict__ out,
                                                         int Hin, int Win) {
  int b = blockIdx.z;
  int iy = blockIdx.y * 2 + threadIdx.y;
  int ix = blockIdx.x * 64 + threadIdx.x;
  if (ix >= Win || iy >= Hin) return;
  const float* p = in + (size_t)b * Hin * Win;
  int rT = (iy == 0) ? 0 : iy - 1;
  int rB = (iy == Hin - 1) ? iy : iy + 1;
  int cL = (ix == 0) ? 0 : ix - 1;
  int cR = (ix == Win - 1) ? ix : ix + 1;
  float wyT1 = (iy == 0) ? 0.f : 0.75f;
  float wyB1 = (iy == Hin - 1) ? 0.f : 0.25f;
  float wxE1 = (ix == 0) ? 0.f : 0.75f;
  float wxO1 = (ix == Win - 1) ? 0.f : 0.25f;
  float wyT0 = 1.f - wyT1, wyB0 = 1.f - wyB1;
  float wxE0 = 1.f - wxE1, wxO0 = 1.f - wxO1;

  const float* rowA = p + (size_t)rT * Win;
  const float* rowM = p + (size_t)iy * Win;
  const float* rowC = p + (size_t)rB * Win;
  float al = rowA[cL], am = rowA[ix], ar = rowA[cR];
  float mL = rowM[cL], mm = rowM[ix], mr = rowM[cR];
  float cl = rowC[cL], cm = rowC[ix], cr = rowC[cR];

  float aE = wxE0 * al + wxE1 * am;
  float aO = wxO0 * am + wxO1 * ar;
  float mE = wxE0 * mL + wxE1 * mm;
  float mO = wxO0 * mm + wxO1 * mr;
  float cE = wxE0 * cl + wxE1 * cm;
  float cO = wxO0 * cm + wxO1 * cr;

  float oTE = wyT0 * aE + wyT1 * mE;
  float oTO = wyT0 * aO + wyT1 * mO;
  float oBE = wyB0 * mE + wyB1 * cE;
  float oBO = wyB0 * mO + wyB1 * cO;

  int Wout = 2 * Win;
  float* ob = out + ((size_t)b * (2 * Hin) + 2 * iy) * Wout + 2 * ix;
  *(float2*)ob = make_float2(oTE, oTO);
  *(float2*)(ob + Wout) = make_float2(oBE, oBO);
}

// ---------------- per-ROI top-784 smallest |gt| (jax top_k tie semantics), 1024 threads ----
__global__ __launch_bounds__(1024) void topk_kernel(const float* __restrict__ ml,
                                                    const int* __restrict__ labels,
                                                    int N, int* __restrict__ sel) {
  int r = blockIdx.x;
  const float* gt = ml + ((size_t)r * K_ + (labels[r] + 1)) * N;
  __shared__ unsigned int hist[256];
  __shared__ unsigned int sh_prefix, sh_remaining, sh_countless;
  __shared__ unsigned int wtot_less[16], wtot_eq[16];
  const int tid = threadIdx.x;
  const int lane = tid & 63;
  const int wv = tid >> 6;

  unsigned int prefix = 0;
  unsigned int remaining = NPTS_;
  unsigned int count_less = 0;
  for (int pass = 0; pass < 4; ++pass) {
    int shift = 24 - 8 * pass;
    if (tid < 256) hist[tid] = 0;
    __syncthreads();
    for (int i = tid; i < N; i += 1024) {
      unsigned int v = __float_as_uint(fabsf(gt[i]));
      bool match = (pass == 0) || ((v >> (shift + 8)) == prefix);
      unsigned int dg = (v >> shift) & 255u;
      if (pass == 0) {
        // exponent byte clusters -> per-wave leader aggregation
        bool active = match;
        while (true) {
          unsigned long long act = __ballot(active);
          if (!act) break;
          int leader = (int)(__ffsll((long long)act) - 1);
          unsigned int ld = __shfl(dg, leader);
          bool same = active && (dg == ld);
          unsigned long long sm = __ballot(same);
          if (lane == leader) atomicAdd(&hist[ld], (unsigned int)__popcll(sm));
          active = active && !same;
        }
      } else if (match) {
        atomicAdd(&hist[dg], 1u);
      }
    }
    __syncthreads();
    if (tid < 64) {
      unsigned int s0 = hist[4 * lane + 0], s1 = hist[4 * lane + 1];
      unsigned int s2 = hist[4 * lane + 2], s3 = hist[4 * lane + 3];
      unsigned int ls = s0 + s1 + s2 + s3;
      unsigned int inc = ls;
#pragma unroll
      for (int d = 1; d < 64; d <<= 1) {
        unsigned int tv = __shfl_up(inc, d);
        if (lane >= d) inc += tv;
      }
      unsigned int exc = inc - ls;
      bool cross = (exc < remaining) && (exc + ls >= remaining);
      if (cross) {  // exactly one lane
        unsigned int before = exc;
        int d = 4 * lane;
        if (before + s0 < remaining) {
          before += s0; d++;
          if (before + s1 < remaining) {
            before += s1; d++;
            if (before + s2 < remaining) { before += s2; d++; }
          }
        }
        sh_prefix = (prefix << 8) | (unsigned int)d;
        sh_remaining = remaining - before;
        sh_countless = count_less + before;
      }
    }
    __syncthreads();
    prefix = sh_prefix;
    remaining = sh_remaining;
    count_less = sh_countless;
    __syncthreads();
  }
  unsigned int vstar = prefix;
  unsigned int need_eq = NPTS_ - count_less;

  unsigned int base_less = 0, base_eq = 0;
  int* selr = sel + (size_t)r * NPTS_;
  for (int base = 0; base < N; base += 1024) {
    int i = base + tid;
    bool less = false, eq = false;
    if (i < N) {
      unsigned int v = __float_as_uint(fabsf(gt[i]));
      less = v < vstar;
      eq = v == vstar;
    }
    unsigned long long ml_ = __ballot(less);
    unsigned long long me_ = __ballot(eq);
    unsigned long long lanemask = (lane == 0) ? 0ull : ((~0ull) >> (64 - lane));
    unsigned int pl = __popcll(ml_ & lanemask);
    unsigned int pe = __popcll(me_ & lanemask);
    if (lane == 0) {
      wtot_less[wv] = (unsigned int)__popcll(ml_);
      wtot_eq[wv] = (unsigned int)__popcll(me_);
    }
    __syncthreads();
    unsigned int off_l = 0, off_e = 0, tot_l = 0, tot_e = 0;
#pragma unroll
    for (int w2 = 0; w2 < 16; ++w2) {
      unsigned int tl = wtot_less[w2], te = wtot_eq[w2];
      if (w2 < wv) { off_l += tl; off_e += te; }
      tot_l += tl;
      tot_e += te;
    }
    if (less) selr[base_less + off_l + pl] = i;
    if (eq) {
      unsigned int er = base_eq + off_e + pe;
      if (er < need_eq) selr[count_less + er] = i;
    }
    base_less += tot_l;
    base_eq += tot_e;
    __syncthreads();
  }
}

// ---------------- sample fine + coarse; write hi/lo bf16 splits (sel==nullptr: iota) ----
__global__ __launch_bounds__(256) void sample_kernel(const int* __restrict__ sel,
                                                     const float* __restrict__ bboxes,
                                                     const float* __restrict__ featT,
                                                     const float* __restrict__ coarseT,
                                                     __hip_bfloat16* __restrict__ Xh,
                                                     __hip_bfloat16* __restrict__ Xl,
                                                     __hip_bfloat16* __restrict__ Cth,
                                                     __hip_bfloat16* __restrict__ Ctl,
                                                     int Wlev, int Hlev) {
  int rp = blockIdx.x;
  int r = rp / NPTS_;
  int idx = sel ? sel[rp] : (rp % NPTS_);
  int tid = threadIdx.x;

  float px = ((float)(idx % Wlev) + 0.5f) / (float)Wlev;
  float py = ((float)(idx / Wlev) + 0.5f) / (float)Hlev;
  float bx0 = bboxes[r * 4 + 0], by0 = bboxes[r * 4 + 1];
  float bw = __fsub_rn(bboxes[r * 4 + 2], bx0);
  float bh = __fsub_rn(bboxes[r * 4 + 3], by0);
  float cx = __fadd_rn(bx0, __fmul_rn(px, bw));
  float cy = __fadd_rn(by0, __fmul_rn(py, bh));

  {
    float gx = __fsub_rn(__fmul_rn(cx, 0.25f), 0.5f);
    float gy = __fsub_rn(__fmul_rn(cy, 0.25f), 0.5f);
    float fxf = floorf(gx), fyf = floorf(gy);
    float fx = __fsub_rn(gx, fxf), fy = __fsub_rn(gy, fyf);
    int x0 = (int)fxf, y0 = (int)fyf;
    float ofx = __fsub_rn(1.f, fx), ofy = __fsub_rn(1.f, fy);
    float w00 = __fmul_rn(ofx, ofy);
    float w10 = __fmul_rn(fx, ofy);
    float w01 = __fmul_rn(ofx, fy);
    float w11 = __fmul_rn(fx, fy);
    bool vx0 = (x0 >= 0) && (x0 < 256), vx1 = (x0 + 1 >= 0) && (x0 + 1 < 256);
    bool vy0 = (y0 >= 0) && (y0 < 256), vy1 = (y0 + 1 >= 0) && (y0 + 1 < 256);
    float W00 = (vx0 && vy0) ? w00 : 0.f;
    float W10 = (vx1 && vy0) ? w10 : 0.f;
    float W01 = (vx0 && vy1) ? w01 : 0.f;
    float W11 = (vx1 && vy1) ? w11 : 0.f;
    int x0c = min(max(x0, 0), 255), x1c = min(max(x0 + 1, 0), 255);
    int y0c = min(max(y0, 0), 255), y1c = min(max(y0 + 1, 0), 255);
    const float* p00 = featT + ((size_t)(y0c * 256 + x0c)) * 256;
    const float* p10 = featT + ((size_t)(y0c * 256 + x1c)) * 256;
    const float* p01 = featT + ((size_t)(y1c * 256 + x0c)) * 256;
    const float* p11 = featT + ((size_t)(y1c * 256 + x1c)) * 256;
    float acc = __fmul_rn(p00[tid], W00);
    acc = __fadd_rn(acc, __fmul_rn(p10[tid], W10));
    acc = __fadd_rn(acc, __fmul_rn(p01[tid], W01));
    acc = __fadd_rn(acc, __fmul_rn(p11[tid], W11));
    __hip_bfloat16 h = __float2bfloat16(acc);
    Xh[(size_t)rp * 256 + tid] = h;
    Xl[(size_t)rp * 256 + tid] = __float2bfloat16(acc - __bfloat162float(h));
  }

  if (tid < 96) {
    float acc = 0.f;
    if (tid < K_) {
      float gx = __fsub_rn(__fmul_rn(px, 7.f), 0.5f);
      float gy = __fsub_rn(__fmul_rn(py, 7.f), 0.5f);
      float fxf = floorf(gx), fyf = floorf(gy);
      float fx = __fsub_rn(gx, fxf), fy = __fsub_rn(gy, fyf);
      int x0 = (int)fxf, y0 = (int)fyf;
      float ofx = __fsub_rn(1.f, fx), ofy = __fsub_rn(1.f, fy);
      float w00 = __fmul_rn(ofx, ofy);
      float w10 = __fmul_rn(fx, ofy);
      float w01 = __fmul_rn(ofx, fy);
      float w11 = __fmul_rn(fx, fy);
      bool vx0 = (x0 >= 0) && (x0 < 7), vx1 = (x0 + 1 >= 0) && (x0 + 1 < 7);
      bool vy0 = (y0 >= 0) && (y0 < 7), vy1 = (y0 + 1 >= 0) && (y0 + 1 < 7);
      float W00 = (vx0 && vy0) ? w00 : 0.f;
      float W10 = (vx1 && vy0) ? w10 : 0.f;
      float W01 = (vx0 && vy1) ? w01 : 0.f;
      float W11 = (vx1 && vy1) ? w11 : 0.f;
      int x0c = min(max(x0, 0), 6), x1c = min(max(x0 + 1, 0), 6);
      int y0c = min(max(y0, 0), 6), y1c = min(max(y0 + 1, 0), 6);
      const float* cb = coarseT + (size_t)r * 49 * K_;
      acc = __fmul_rn(cb[(size_t)(y0c * 7 + x0c) * K_ + tid], W00);
      acc = __fadd_rn(acc, __fmul_rn(cb[(size_t)(y0c * 7 + x1c) * K_ + tid], W10));
      acc = __fadd_rn(acc, __fmul_rn(cb[(size_t)(y1c * 7 + x0c) * K_ + tid], W01));
      acc = __fadd_rn(acc, __fmul_rn(cb[(size_t)(y1c * 7 + x1c) * K_ + tid], W11));
    }
    __hip_bfloat16 h = __float2bfloat16(acc);
    Cth[(size_t)rp * 96 + tid] = h;
    Ctl[(size_t)rp * 96 + tid] = __float2bfloat16(acc - __bfloat162float(h));
  }
}

// ---------------- FUSED 4-layer point head, v6b ----------------
// 4 waves x (64 pts x 64 cols); B (global Wpk) 2-deep ping-pong; A direct from LDS;
// coarse-lo (Tl) global fragments prefetched one chunk ahead (new in v6b).
template <int TERMS>
__global__ __launch_bounds__(256, 2) void fused_head_kernel(
    const __hip_bfloat16* __restrict__ Ah, const __hip_bfloat16* __restrict__ Al,
    const __hip_bfloat16* __restrict__ Th, const __hip_bfloat16* __restrict__ Tl,
    const __hip_bfloat16* __restrict__ Wpk,
    const float* __restrict__ bias_all, float* __restrict__ PL) {
  constexpr int XPLANE = 11 * 4096;  // 45056 B (hi)
  constexpr int XLO = 8 * 4096;      // 32768 B (lo, activation chunks only)
  __shared__ char lds[(TERMS == 3) ? XPLANE + XLO : XPLANE];
  char* Xh = lds;
  char* Xl = lds + XPLANE;  // chunks 0..7 only; TERMS==3

  const int tid = threadIdx.x;
  const int lane = tid & 63;
  const int w = tid >> 6;
  const int g = lane >> 4;
  const int lane15 = lane & 15;
  const int m0 = blockIdx.x * 64;

  // ---- stage X once (pre-swizzled global source, linear LDS dest) ----
  {
    const int srow = tid >> 2;
    const int sp = tid & 3;
    const int sx = sp ^ ((srow >> 1) & 3);
#pragma unroll
    for (int kt = 0; kt < 8; ++kt) {
      size_t off = (((size_t)(m0 + srow)) * 256 + (size_t)kt * 32 + (size_t)sx * 8) * 2;
      GLDS16((const char*)Ah + off, Xh + kt * 4096 + w * 1024);
      if constexpr (TERMS == 3) GLDS16((const char*)Al + off, Xl + kt * 4096 + w * 1024);
    }
#pragma unroll
    for (int kt = 8; kt < 11; ++kt) {
      size_t off = (((size_t)(m0 + srow)) * 96 + (size_t)(kt - 8) * 32 + (size_t)sx * 8) * 2;
      GLDS16((const char*)Th + off, Xh + kt * 4096 + w * 1024);
    }
  }
  asm volatile("s_waitcnt vmcnt(0)" ::: "memory");
  __syncthreads();

  int offA[4];
#pragma unroll
  for (int i = 0; i < 4; ++i) {
    int rowA = i * 16 + lane15;
    offA[i] = rowA * 64 + ((g ^ ((rowA >> 1) & 3)) << 4);
  }

#pragma unroll 1
  for (int L = 0; L < 4; ++L) {
    if (L == 3 && w >= 2) break;  // Wp cols 128..255 all-zero
    const __hip_bfloat16* WL = Wpk + (size_t)L * (11 * 16 * 2 * 512);

    f32x4 acc[4][4];
#pragma unroll
    for (int i = 0; i < 4; ++i)
#pragma unroll
      for (int j = 0; j < 4; ++j) acc[i][j] = (f32x4){0.f, 0.f, 0.f, 0.f};

    short8 a_h[4], a_l[4], b_h[2][4], b_l[2][4], tl_buf[2][4];

    auto loadB = [&](int buf, int kt) {
#pragma unroll
      for (int j = 0; j < 4; ++j) {
        const __hip_bfloat16* bp =
            WL + (((size_t)kt * 16 + (w * 4 + j)) * 2) * 512 + (size_t)lane * 8;
        b_h[buf][j] = *(const short8*)bp;
        if constexpr (TERMS == 3) b_l[buf][j] = *(const short8*)(bp + 512);
      }
    };
    auto loadTl = [&](int buf, int kt) {  // kt in 8..10, TERMS==3 only
#pragma unroll
      for (int i = 0; i < 4; ++i)
        tl_buf[buf][i] = *(const short8*)((const char*)Tl +
            (((size_t)(m0 + i * 16 + lane15)) * 96 + (size_t)(kt - 8) * 32 +
             (size_t)g * 8) * 2);
    };

    loadB(0, 0);

#pragma unroll
    for (int kt = 0; kt < 11; ++kt) {
      const int cb = kt & 1;
      if (kt < 10) {
        loadB(cb ^ 1, kt + 1);  // B prefetch (global, long latency)
        if constexpr (TERMS == 3) {
          if (kt + 1 >= 8) loadTl((kt + 1) & 1, kt + 1);  // coarse-lo prefetch
        }
      }
      __builtin_amdgcn_sched_barrier(0);  // pin: prefetch issues BEFORE the MFMA cluster
      // A direct from LDS (short latency; hidden by co-resident wave)
#pragma unroll
      for (int i = 0; i < 4; ++i) {
        a_h[i] = *(const short8*)(Xh + kt * 4096 + offA[i]);
        if constexpr (TERMS == 3) {
          if (kt < 8)
            a_l[i] = *(const short8*)(Xl + kt * 4096 + offA[i]);
          else
            a_l[i] = tl_buf[kt & 1][i];
        }
      }
      __builtin_amdgcn_s_setprio(1);
#pragma unroll
      for (int i = 0; i < 4; ++i)
#pragma unroll
        for (int j = 0; j < 4; ++j) {
          acc[i][j] = __builtin_amdgcn_mfma_f32_16x16x32_bf16(a_h[i], b_h[cb][j], acc[i][j], 0, 0, 0);
          if constexpr (TERMS == 3) {
            acc[i][j] = __builtin_amdgcn_mfma_f32_16x16x32_bf16(a_h[i], b_l[cb][j], acc[i][j], 0, 0, 0);
            acc[i][j] = __builtin_amdgcn_mfma_f32_16x16x32_bf16(a_l[i], b_h[cb][j], acc[i][j], 0, 0, 0);
          }
        }
      __builtin_amdgcn_s_setprio(0);
      __builtin_amdgcn_sched_barrier(0);
    }

    if (L < 3) {
      __syncthreads();  // all waves done READING X before overwrite
#pragma unroll
      for (int j = 0; j < 4; ++j) {
        int o = w * 64 + j * 16 + lane15;
        float bv = bias_all[L * 256 + o];
        int kch = o >> 5;
        int s0 = (o >> 3) & 3;
        int e = o & 7;
#pragma unroll
        for (int i = 0; i < 4; ++i) {
          int mb = i * 16 + g * 4;
#pragma unroll
          for (int r = 0; r < 4; ++r) {
            int m = mb + r;
            float v = fmaxf(acc[i][j][r] + bv, 0.f);
            __hip_bfloat16 h = __float2bfloat16(v);
            int boff = kch * 4096 + m * 64 + ((s0 ^ ((m >> 1) & 3)) << 4) + e * 2;
            *(__hip_bfloat16*)(Xh + boff) = h;
            if constexpr (TERMS == 3)
              *(__hip_bfloat16*)(Xl + boff) = __float2bfloat16(v - __bfloat162float(h));
          }
        }
      }
      __syncthreads();
    } else {
      // final layer: bias only, f32 out [rp][128] (waves 0,1 only)
#pragma unroll
      for (int j = 0; j < 4; ++j) {
        int o = w * 64 + j * 16 + lane15;
        float bv = bias_all[768 + o];
#pragma unroll
        for (int i = 0; i < 4; ++i) {
          int mb = i * 16 + g * 4;
#pragma unroll
          for (int r = 0; r < 4; ++r)
            PL[(size_t)(m0 + mb + r) * 128 + o] = acc[i][j][r] + bv;
        }
      }
    }
  }
}

// ---------------- scatter head outputs into ml (sel==nullptr: iota) ----------------
__global__ void scatter_kernel(const float* __restrict__ PL, const int* __restrict__ sel,
                               float* __restrict__ ml, int Nlev) {
  int t = blockIdx.x * 256 + threadIdx.x;
  if (t >= R_ * NPTS_ * K_) return;
  int k = t % K_;
  int rp = t / K_;
  int i = sel ? sel[rp] : (rp % NPTS_);
  int r = rp / NPTS_;
  ml[((size_t)r * K_ + k) * Nlev + i] = PL[(size_t)rp * 128 + k];
}

extern "C" void kernel_launch(void* const* d_in, const int* in_sizes, int n_in,
                              void* d_out, int out_size, void* d_ws, size_t ws_size,
                              hipStream_t stream) {
  (void)in_sizes; (void)n_in; (void)out_size; (void)ws_size;
  const float* feat = (const float*)d_in[0];
  const float* bboxes = (const float*)d_in[1];
  const int* labels = (const int*)d_in[2];
  const float* coarse = (const float*)d_in[3];
  const float* W1 = (const float*)d_in[4];
  const float* b1 = (const float*)d_in[5];
  const float* W2 = (const float*)d_in[6];
  const float* b2 = (const float*)d_in[7];
  const float* W3 = (const float*)d_in[8];
  const float* b3 = (const float*)d_in[9];
  const float* Wp = (const float*)d_in[10];
  const float* bp = (const float*)d_in[11];
  float* out = (float*)d_out;

  char* p = (char*)d_ws;
  auto alloc = [&](size_t bytes) { char* r = p; p += (bytes + 255) & ~(size_t)255; return r; };
  float* featT = (float*)alloc(16777216ull * 4);
  float* coarseT = (float*)alloc(254016ull * 4);
  float* ml14 = (float*)alloc(1016064ull * 4);
  float* ml28 = (float*)alloc(4064256ull * 4);
  float* ml56 = (float*)alloc(16257024ull * 4);
  float* PL = (float*)alloc(6422528ull * 4);
  int* sel = (int*)alloc(50176ull * 4);
  __hip_bfloat16* Xa_h = (__hip_bfloat16*)alloc(12845056ull * 2);
  __hip_bfloat16* Xa_l = (__hip_bfloat16*)alloc(12845056ull * 2);
  __hip_bfloat16* Ct_h = (__hip_bfloat16*)alloc(4816896ull * 2);
  __hip_bfloat16* Ct_l = (__hip_bfloat16*)alloc(4816896ull * 2);
  __hip_bfloat16* Wpk = (__hip_bfloat16*)alloc(720896ull * 2);
  float* bias_all = (float*)alloc(1024ull * 4);

  const int N = R_ * NPTS_;  // 50176
  const int B = R_ * K_;     // 5184

  transpose_feat_kernel<<<dim3(8, 8, 256), dim3(32, 8), 0, stream>>>(feat, featT);
  prep_all_kernel<<<1349, 256, 0, stream>>>(W1, W2, W3, Wp, b1, b2, b3, bp, coarse, Wpk, bias_all, coarseT);

  // step 0: 7 -> 14 (no refine)
  upsample2x_kernel<<<dim3(1, 4, B), dim3(64, 2), 0, stream>>>(coarse, ml14, 7, 7);

  // ---- step 1: 14 -> 28, refine ALL 784 points (exact 3-term head) ----
  upsample2x_kernel<<<dim3(1, 7, B), dim3(64, 2), 0, stream>>>(ml14, ml28, 14, 14);
  sample_kernel<<<N, 256, 0, stream>>>(nullptr, bboxes, featT, coarseT, Xa_h, Xa_l, Ct_h, Ct_l, 28, 28);
  fused_head_kernel<3><<<784, 256, 0, stream>>>(Xa_h, Xa_l, Ct_h, Ct_l, Wpk, bias_all, PL);
  scatter_kernel<<<15876, 256, 0, stream>>>(PL, nullptr, ml28, 784);

  // ---- step 2: 28 -> 56, refine top-784 of 3136 (exact 3-term head) ----
  upsample2x_kernel<<<dim3(1, 14, B), dim3(64, 2), 0, stream>>>(ml28, ml56, 28, 28);
  topk_kernel<<<R_, 1024, 0, stream>>>(ml56, labels, 3136, sel);
  sample_kernel<<<N, 256, 0, stream>>>(sel, bboxes, featT, coarseT, Xa_h, Xa_l, Ct_h, Ct_l, 56, 56);
  fused_head_kernel<3><<<784, 256, 0, stream>>>(Xa_h, Xa_l, Ct_h, Ct_l, Wpk, bias_all, PL);
  scatter_kernel<<<15876, 256, 0, stream>>>(PL, sel, ml56, 3136);

  // ---- step 3: 56 -> 112 (into d_out), refine top-784 of 12544 (1-term bf16 head) ----
  upsample2x_kernel<<<dim3(1, 28, B), dim3(64, 2), 0, stream>>>(ml56, out, 56, 56);
  topk_kernel<<<R_, 1024, 0, stream>>>(out, labels, 12544, sel);
  sample_kernel<<<N, 256, 0, stream>>>(sel, bboxes, featT, coarseT, Xa_h, Xa_l, Ct_h, Ct_l, 112, 112);
  fused_head_kernel<1><<<784, 256, 0, stream>>>(Xa_h, nullptr, Ct_h, nullptr, Wpk, bias_all, PL);
  scatter_kernel<<<15876, 256, 0, stream>>>(PL, sel, out, 12544);
}

// Round 13
// 763.904 us; speedup vs baseline: 1.2651x; 1.0884x over previous
//
#include <hip/hip_runtime.h>
#include <hip/hip_bf16.h>
#include <cstdint>
#include <cstddef>

#define R_ 64
#define K_ 81
#define NPTS_ 784

typedef __attribute__((ext_vector_type(8))) short short8;
typedef __attribute__((ext_vector_type(4))) float f32x4;

#define GLDS16(G, L)                                                           \
  __builtin_amdgcn_global_load_lds(                                            \
      (__attribute__((address_space(1))) void*)(void*)(G),                     \
      (__attribute__((address_space(3))) void*)(L), 16, 0, 0)

// ---------------- transpose feat [C][H][W] -> [H][W][C] ----------------
__global__ __launch_bounds__(256) void transpose_feat_kernel(const float* __restrict__ in,
                                                             float* __restrict__ out) {
  __shared__ float tile[32][33];
  int y = blockIdx.z;
  int x0 = blockIdx.x * 32, c0 = blockIdx.y * 32;
  int tx = threadIdx.x, ty = threadIdx.y;
#pragma unroll
  for (int j = 0; j < 32; j += 8)
    tile[ty + j][tx] = in[(size_t)(c0 + ty + j) * 65536 + (size_t)y * 256 + x0 + tx];
  __syncthreads();
#pragma unroll
  for (int j = 0; j < 32; j += 8)
    out[((size_t)y * 256 + (x0 + ty + j)) * 256 + c0 + tx] = tile[tx][ty + j];
}

// ---------------- merged prep: W pack (hi/lo) + bias pack + coarse transpose ----------------
__global__ void prep_all_kernel(const float* __restrict__ W1, const float* __restrict__ W2,
                                const float* __restrict__ W3, const float* __restrict__ Wp,
                                const float* __restrict__ b1, const float* __restrict__ b2,
                                const float* __restrict__ b3, const float* __restrict__ bp,
                                const float* __restrict__ coarse_in,
                                __hip_bfloat16* __restrict__ Wpk, float* __restrict__ bias_all,
                                float* __restrict__ coarseT) {
  int t = blockIdx.x * 256 + threadIdx.x;
  if (t < 90112) {
    int lane = t & 63;
    int t2 = t >> 6;
    int hl = t2 & 1;
    t2 >>= 1;
    int jg = t2 & 15;
    t2 >>= 4;
    int kt = t2 % 11;
    int L = t2 / 11;
    int o = jg * 16 + (lane & 15);
    int kbase = kt * 32 + (lane >> 4) * 8;
    const float* Wsrc = (L == 0) ? W1 : (L == 1) ? W2 : (L == 2) ? W3 : Wp;
    int Omax = (L == 3) ? 81 : 256;
    __hip_bfloat16 outv[8];
#pragma unroll
    for (int e = 0; e < 8; ++e) {
      int k = kbase + e;
      float v = (o < Omax && k < 337) ? Wsrc[o * 337 + k] : 0.f;
      __hip_bfloat16 h = __float2bfloat16(v);
      outv[e] = hl ? __float2bfloat16(v - __bfloat162float(h)) : h;
    }
    *(short8*)(Wpk + (size_t)t * 8) = *(const short8*)outv;
  } else if (t < 90112 + 1024) {
    int k = t - 90112;
    float v = 0.f;
    if (k < 256) v = b1[k];
    else if (k < 512) v = b2[k - 256];
    else if (k < 768) v = b3[k - 512];
    else if (k < 768 + 81) v = bp[k - 768];
    bias_all[k] = v;
  } else {
    int t2 = t - 91136;
    if (t2 < R_ * 49 * K_) {
      int k = t2 % K_;
      int t3 = t2 / K_;
      int pos = t3 % 49;
      int r = t3 / 49;
      coarseT[t2] = coarse_in[((size_t)r * K_ + k) * 49 + pos];
    }
  }
}

// ---------------- quad upsample core (jax.image.resize linear semantics) ----------------
__device__ __forceinline__ void quad_upsample(const float* __restrict__ p, int Hin, int Win,
                                              int iy, int ix, float& oTE, float& oTO,
                                              float& oBE, float& oBO) {
  int rT = (iy == 0) ? 0 : iy - 1;
  int rB = (iy == Hin - 1) ? iy : iy + 1;
  int cL = (ix == 0) ? 0 : ix - 1;
  int cR = (ix == Win - 1) ? ix : ix + 1;
  float wyT1 = (iy == 0) ? 0.f : 0.75f;
  float wyB1 = (iy == Hin - 1) ? 0.f : 0.25f;
  float wxE1 = (ix == 0) ? 0.f : 0.75f;
  float wxO1 = (ix == Win - 1) ? 0.f : 0.25f;
  float wyT0 = 1.f - wyT1, wyB0 = 1.f - wyB1;
  float wxE0 = 1.f - wxE1, wxO0 = 1.f - wxO1;
  const float* rowA = p + (size_t)rT * Win;
  const float* rowM = p + (size_t)iy * Win;
  const float* rowC = p + (size_t)rB * Win;
  float al = rowA[cL], am = rowA[ix], ar = rowA[cR];
  float mL = rowM[cL], mm = rowM[ix], mr = rowM[cR];
  float cl = rowC[cL], cm = rowC[ix], cr = rowC[cR];
  float aE = wxE0 * al + wxE1 * am;
  float aO = wxO0 * am + wxO1 * ar;
  float mE = wxE0 * mL + wxE1 * mm;
  float mO = wxO0 * mm + wxO1 * mr;
  float cE = wxE0 * cl + wxE1 * cm;
  float cO = wxO0 * cm + wxO1 * cr;
  oTE = wyT0 * aE + wyT1 * mE;
  oTO = wyT0 * aO + wyT1 * mO;
  oBE = wyB0 * mE + wyB1 * cE;
  oBO = wyB0 * mO + wyB1 * cO;
}

// ---------------- 2x bilinear upsample (all channels) ----------------
__global__ __launch_bounds__(128) void upsample2x_kernel(const float* __restrict__ in,
                                                         float* __restrict__ out,
                                                         int Hin, int Win) {
  int b = blockIdx.z;
  int iy = blockIdx.y * 2 + threadIdx.y;
  int ix = blockIdx.x * 64 + threadIdx.x;
  if (ix >= Win || iy >= Hin) return;
  const float* p = in + (size_t)b * Hin * Win;
  float oTE, oTO, oBE, oBO;
  quad_upsample(p, Hin, Win, iy, ix, oTE, oTO, oBE, oBO);
  int Wout = 2 * Win;
  float* ob = out + ((size_t)b * (2 * Hin) + 2 * iy) * Wout + 2 * ix;
  *(float2*)ob = make_float2(oTE, oTO);
  *(float2*)(ob + Wout) = make_float2(oBE, oBO);
}

// ---------------- gt-channel-only 2x upsample: ml56[r][gt] -> gtbuf[r][12544] ----------------
__global__ __launch_bounds__(128) void upsample2x_gt_kernel(const float* __restrict__ ml56,
                                                            const int* __restrict__ labels,
                                                            float* __restrict__ gtbuf) {
  int r = blockIdx.z;
  int iy = blockIdx.y * 2 + threadIdx.y;
  int ix = blockIdx.x * 64 + threadIdx.x;
  if (ix >= 56 || iy >= 56) return;
  const float* p = ml56 + ((size_t)r * K_ + (labels[r] + 1)) * 3136;
  float oTE, oTO, oBE, oBO;
  quad_upsample(p, 56, 56, iy, ix, oTE, oTO, oBE, oBO);
  float* ob = gtbuf + ((size_t)r * 112 + 2 * iy) * 112 + 2 * ix;
  *(float2*)ob = make_float2(oTE, oTO);
  *(float2*)(ob + 112) = make_float2(oBE, oBO);
}

// ---------------- final fused upsample + select: out = resize(ml56), sel positions = PL ----
__global__ __launch_bounds__(128) void upsample2x_sel_kernel(const float* __restrict__ ml56,
                                                             const unsigned short* __restrict__ map,
                                                             const float* __restrict__ PL,
                                                             float* __restrict__ out) {
  int b = blockIdx.z;  // r*81 + k
  int r = b / K_;
  int k = b - r * K_;
  int iy = blockIdx.y * 2 + threadIdx.y;
  int ix = blockIdx.x * 64 + threadIdx.x;
  if (ix >= 56 || iy >= 56) return;
  const float* p = ml56 + (size_t)b * 3136;
  float oTE, oTO, oBE, oBO;
  quad_upsample(p, 56, 56, iy, ix, oTE, oTO, oBE, oBO);
  int oy = 2 * iy, ox = 2 * ix;
  const unsigned short* mr = map + (size_t)r * 12544;
  unsigned short r0 = mr[oy * 112 + ox], r1 = mr[oy * 112 + ox + 1];
  unsigned short r2 = mr[(oy + 1) * 112 + ox], r3 = mr[(oy + 1) * 112 + ox + 1];
  if (r0 != 0xFFFFu) oTE = PL[((size_t)r * NPTS_ + r0) * 128 + k];
  if (r1 != 0xFFFFu) oTO = PL[((size_t)r * NPTS_ + r1) * 128 + k];
  if (r2 != 0xFFFFu) oBE = PL[((size_t)r * NPTS_ + r2) * 128 + k];
  if (r3 != 0xFFFFu) oBO = PL[((size_t)r * NPTS_ + r3) * 128 + k];
  float* ob = out + ((size_t)b * 112 + oy) * 112 + ox;
  *(float2*)ob = make_float2(oTE, oTO);
  *(float2*)(ob + 112) = make_float2(oBE, oBO);
}

// ---------------- rank map init + build ----------------
__global__ void mapinit_kernel(unsigned short* __restrict__ map) {
  int t = blockIdx.x * 256 + threadIdx.x;
  if (t < R_ * 12544) map[t] = 0xFFFFu;
}
__global__ void mapbuild_kernel(const int* __restrict__ sel, unsigned short* __restrict__ map) {
  int t = blockIdx.x * 256 + threadIdx.x;
  if (t < R_ * NPTS_) {
    int r = t / NPTS_;
    map[(size_t)r * 12544 + sel[t]] = (unsigned short)(t % NPTS_);
  }
}

// ---------------- per-ROI top-784 smallest |gt| (jax top_k tie semantics), 1024 threads ----
__global__ __launch_bounds__(1024) void topk_kernel(const float* __restrict__ ml,
                                                    const int* __restrict__ labels,
                                                    const float* __restrict__ gtdirect,
                                                    int N, int* __restrict__ sel) {
  int r = blockIdx.x;
  const float* gt = gtdirect ? (gtdirect + (size_t)r * N)
                             : (ml + ((size_t)r * K_ + (labels[r] + 1)) * N);
  __shared__ unsigned int hist[256];
  __shared__ unsigned int sh_prefix, sh_remaining, sh_countless;
  __shared__ unsigned int wtot_less[16], wtot_eq[16];
  const int tid = threadIdx.x;
  const int lane = tid & 63;
  const int wv = tid >> 6;

  unsigned int prefix = 0;
  unsigned int remaining = NPTS_;
  unsigned int count_less = 0;
  for (int pass = 0; pass < 4; ++pass) {
    int shift = 24 - 8 * pass;
    if (tid < 256) hist[tid] = 0;
    __syncthreads();
    for (int i = tid; i < N; i += 1024) {
      unsigned int v = __float_as_uint(fabsf(gt[i]));
      bool match = (pass == 0) || ((v >> (shift + 8)) == prefix);
      unsigned int dg = (v >> shift) & 255u;
      if (pass == 0) {
        bool active = match;
        while (true) {
          unsigned long long act = __ballot(active);
          if (!act) break;
          int leader = (int)(__ffsll((long long)act) - 1);
          unsigned int ld = __shfl(dg, leader);
          bool same = active && (dg == ld);
          unsigned long long sm = __ballot(same);
          if (lane == leader) atomicAdd(&hist[ld], (unsigned int)__popcll(sm));
          active = active && !same;
        }
      } else if (match) {
        atomicAdd(&hist[dg], 1u);
      }
    }
    __syncthreads();
    if (tid < 64) {
      unsigned int s0 = hist[4 * lane + 0], s1 = hist[4 * lane + 1];
      unsigned int s2 = hist[4 * lane + 2], s3 = hist[4 * lane + 3];
      unsigned int ls = s0 + s1 + s2 + s3;
      unsigned int inc = ls;
#pragma unroll
      for (int d = 1; d < 64; d <<= 1) {
        unsigned int tv = __shfl_up(inc, d);
        if (lane >= d) inc += tv;
      }
      unsigned int exc = inc - ls;
      bool cross = (exc < remaining) && (exc + ls >= remaining);
      if (cross) {
        unsigned int before = exc;
        int d = 4 * lane;
        if (before + s0 < remaining) {
          before += s0; d++;
          if (before + s1 < remaining) {
            before += s1; d++;
            if (before + s2 < remaining) { before += s2; d++; }
          }
        }
        sh_prefix = (prefix << 8) | (unsigned int)d;
        sh_remaining = remaining - before;
        sh_countless = count_less + before;
      }
    }
    __syncthreads();
    prefix = sh_prefix;
    remaining = sh_remaining;
    count_less = sh_countless;
    __syncthreads();
  }
  unsigned int vstar = prefix;
  unsigned int need_eq = NPTS_ - count_less;

  unsigned int base_less = 0, base_eq = 0;
  int* selr = sel + (size_t)r * NPTS_;
  for (int base = 0; base < N; base += 1024) {
    int i = base + tid;
    bool less = false, eq = false;
    if (i < N) {
      unsigned int v = __float_as_uint(fabsf(gt[i]));
      less = v < vstar;
      eq = v == vstar;
    }
    unsigned long long ml_ = __ballot(less);
    unsigned long long me_ = __ballot(eq);
    unsigned long long lanemask = (lane == 0) ? 0ull : ((~0ull) >> (64 - lane));
    unsigned int pl = __popcll(ml_ & lanemask);
    unsigned int pe = __popcll(me_ & lanemask);
    if (lane == 0) {
      wtot_less[wv] = (unsigned int)__popcll(ml_);
      wtot_eq[wv] = (unsigned int)__popcll(me_);
    }
    __syncthreads();
    unsigned int off_l = 0, off_e = 0, tot_l = 0, tot_e = 0;
#pragma unroll
    for (int w2 = 0; w2 < 16; ++w2) {
      unsigned int tl = wtot_less[w2], te = wtot_eq[w2];
      if (w2 < wv) { off_l += tl; off_e += te; }
      tot_l += tl;
      tot_e += te;
    }
    if (less) selr[base_less + off_l + pl] = i;
    if (eq) {
      unsigned int er = base_eq + off_e + pe;
      if (er < need_eq) selr[count_less + er] = i;
    }
    base_less += tot_l;
    base_eq += tot_e;
    __syncthreads();
  }
}

// ---------------- sample fine + coarse; write hi/lo bf16 splits (sel==nullptr: iota) ----
__global__ __launch_bounds__(256) void sample_kernel(const int* __restrict__ sel,
                                                     const float* __restrict__ bboxes,
                                                     const float* __restrict__ featT,
                                                     const float* __restrict__ coarseT,
                                                     __hip_bfloat16* __restrict__ Xh,
                                                     __hip_bfloat16* __restrict__ Xl,
                                                     __hip_bfloat16* __restrict__ Cth,
                                                     __hip_bfloat16* __restrict__ Ctl,
                                                     int Wlev, int Hlev) {
  int rp = blockIdx.x;
  int r = rp / NPTS_;
  int idx = sel ? sel[rp] : (rp % NPTS_);
  int tid = threadIdx.x;

  float px = ((float)(idx % Wlev) + 0.5f) / (float)Wlev;
  float py = ((float)(idx / Wlev) + 0.5f) / (float)Hlev;
  float bx0 = bboxes[r * 4 + 0], by0 = bboxes[r * 4 + 1];
  float bw = __fsub_rn(bboxes[r * 4 + 2], bx0);
  float bh = __fsub_rn(bboxes[r * 4 + 3], by0);
  float cx = __fadd_rn(bx0, __fmul_rn(px, bw));
  float cy = __fadd_rn(by0, __fmul_rn(py, bh));

  {
    float gx = __fsub_rn(__fmul_rn(cx, 0.25f), 0.5f);
    float gy = __fsub_rn(__fmul_rn(cy, 0.25f), 0.5f);
    float fxf = floorf(gx), fyf = floorf(gy);
    float fx = __fsub_rn(gx, fxf), fy = __fsub_rn(gy, fyf);
    int x0 = (int)fxf, y0 = (int)fyf;
    float ofx = __fsub_rn(1.f, fx), ofy = __fsub_rn(1.f, fy);
    float w00 = __fmul_rn(ofx, ofy);
    float w10 = __fmul_rn(fx, ofy);
    float w01 = __fmul_rn(ofx, fy);
    float w11 = __fmul_rn(fx, fy);
    bool vx0 = (x0 >= 0) && (x0 < 256), vx1 = (x0 + 1 >= 0) && (x0 + 1 < 256);
    bool vy0 = (y0 >= 0) && (y0 < 256), vy1 = (y0 + 1 >= 0) && (y0 + 1 < 256);
    float W00 = (vx0 && vy0) ? w00 : 0.f;
    float W10 = (vx1 && vy0) ? w10 : 0.f;
    float W01 = (vx0 && vy1) ? w01 : 0.f;
    float W11 = (vx1 && vy1) ? w11 : 0.f;
    int x0c = min(max(x0, 0), 255), x1c = min(max(x0 + 1, 0), 255);
    int y0c = min(max(y0, 0), 255), y1c = min(max(y0 + 1, 0), 255);
    const float* p00 = featT + ((size_t)(y0c * 256 + x0c)) * 256;
    const float* p10 = featT + ((size_t)(y0c * 256 + x1c)) * 256;
    const float* p01 = featT + ((size_t)(y1c * 256 + x0c)) * 256;
    const float* p11 = featT + ((size_t)(y1c * 256 + x1c)) * 256;
    float acc = __fmul_rn(p00[tid], W00);
    acc = __fadd_rn(acc, __fmul_rn(p10[tid], W10));
    acc = __fadd_rn(acc, __fmul_rn(p01[tid], W01));
    acc = __fadd_rn(acc, __fmul_rn(p11[tid], W11));
    __hip_bfloat16 h = __float2bfloat16(acc);
    Xh[(size_t)rp * 256 + tid] = h;
    Xl[(size_t)rp * 256 + tid] = __float2bfloat16(acc - __bfloat162float(h));
  }

  if (tid < 96) {
    float acc = 0.f;
    if (tid < K_) {
      float gx = __fsub_rn(__fmul_rn(px, 7.f), 0.5f);
      float gy = __fsub_rn(__fmul_rn(py, 7.f), 0.5f);
      float fxf = floorf(gx), fyf = floorf(gy);
      float fx = __fsub_rn(gx, fxf), fy = __fsub_rn(gy, fyf);
      int x0 = (int)fxf, y0 = (int)fyf;
      float ofx = __fsub_rn(1.f, fx), ofy = __fsub_rn(1.f, fy);
      float w00 = __fmul_rn(ofx, ofy);
      float w10 = __fmul_rn(fx, ofy);
      float w01 = __fmul_rn(ofx, fy);
      float w11 = __fmul_rn(fx, fy);
      bool vx0 = (x0 >= 0) && (x0 < 7), vx1 = (x0 + 1 >= 0) && (x0 + 1 < 7);
      bool vy0 = (y0 >= 0) && (y0 < 7), vy1 = (y0 + 1 >= 0) && (y0 + 1 < 7);
      float W00 = (vx0 && vy0) ? w00 : 0.f;
      float W10 = (vx1 && vy0) ? w10 : 0.f;
      float W01 = (vx0 && vy1) ? w01 : 0.f;
      float W11 = (vx1 && vy1) ? w11 : 0.f;
      int x0c = min(max(x0, 0), 6), x1c = min(max(x0 + 1, 0), 6);
      int y0c = min(max(y0, 0), 6), y1c = min(max(y0 + 1, 0), 6);
      const float* cb = coarseT + (size_t)r * 49 * K_;
      acc = __fmul_rn(cb[(size_t)(y0c * 7 + x0c) * K_ + tid], W00);
      acc = __fadd_rn(acc, __fmul_rn(cb[(size_t)(y0c * 7 + x1c) * K_ + tid], W10));
      acc = __fadd_rn(acc, __fmul_rn(cb[(size_t)(y1c * 7 + x0c) * K_ + tid], W01));
      acc = __fadd_rn(acc, __fmul_rn(cb[(size_t)(y1c * 7 + x1c) * K_ + tid], W11));
    }
    __hip_bfloat16 h = __float2bfloat16(acc);
    Cth[(size_t)rp * 96 + tid] = h;
    Ctl[(size_t)rp * 96 + tid] = __float2bfloat16(acc - __bfloat162float(h));
  }
}

// ---------------- FUSED 4-layer point head, v6b (unchanged from R12) ----------------
template <int TERMS>
__global__ __launch_bounds__(256, 2) void fused_head_kernel(
    const __hip_bfloat16* __restrict__ Ah, const __hip_bfloat16* __restrict__ Al,
    const __hip_bfloat16* __restrict__ Th, const __hip_bfloat16* __restrict__ Tl,
    const __hip_bfloat16* __restrict__ Wpk,
    const float* __restrict__ bias_all, float* __restrict__ PL) {
  constexpr int XPLANE = 11 * 4096;
  constexpr int XLO = 8 * 4096;
  __shared__ char lds[(TERMS == 3) ? XPLANE + XLO : XPLANE];
  char* Xh = lds;
  char* Xl = lds + XPLANE;

  const int tid = threadIdx.x;
  const int lane = tid & 63;
  const int w = tid >> 6;
  const int g = lane >> 4;
  const int lane15 = lane & 15;
  const int m0 = blockIdx.x * 64;

  {
    const int srow = tid >> 2;
    const int sp = tid & 3;
    const int sx = sp ^ ((srow >> 1) & 3);
#pragma unroll
    for (int kt = 0; kt < 8; ++kt) {
      size_t off = (((size_t)(m0 + srow)) * 256 + (size_t)kt * 32 + (size_t)sx * 8) * 2;
      GLDS16((const char*)Ah + off, Xh + kt * 4096 + w * 1024);
      if constexpr (TERMS == 3) GLDS16((const char*)Al + off, Xl + kt * 4096 + w * 1024);
    }
#pragma unroll
    for (int kt = 8; kt < 11; ++kt) {
      size_t off = (((size_t)(m0 + srow)) * 96 + (size_t)(kt - 8) * 32 + (size_t)sx * 8) * 2;
      GLDS16((const char*)Th + off, Xh + kt * 4096 + w * 1024);
    }
  }
  asm volatile("s_waitcnt vmcnt(0)" ::: "memory");
  __syncthreads();

  int offA[4];
#pragma unroll
  for (int i = 0; i < 4; ++i) {
    int rowA = i * 16 + lane15;
    offA[i] = rowA * 64 + ((g ^ ((rowA >> 1) & 3)) << 4);
  }

#pragma unroll 1
  for (int L = 0; L < 4; ++L) {
    if (L == 3 && w >= 2) break;
    const __hip_bfloat16* WL = Wpk + (size_t)L * (11 * 16 * 2 * 512);

    f32x4 acc[4][4];
#pragma unroll
    for (int i = 0; i < 4; ++i)
#pragma unroll
      for (int j = 0; j < 4; ++j) acc[i][j] = (f32x4){0.f, 0.f, 0.f, 0.f};

    short8 a_h[4], a_l[4], b_h[2][4], b_l[2][4], tl_buf[2][4];

    auto loadB = [&](int buf, int kt) {
#pragma unroll
      for (int j = 0; j < 4; ++j) {
        const __hip_bfloat16* bp =
            WL + (((size_t)kt * 16 + (w * 4 + j)) * 2) * 512 + (size_t)lane * 8;
        b_h[buf][j] = *(const short8*)bp;
        if constexpr (TERMS == 3) b_l[buf][j] = *(const short8*)(bp + 512);
      }
    };
    auto loadTl = [&](int buf, int kt) {
#pragma unroll
      for (int i = 0; i < 4; ++i)
        tl_buf[buf][i] = *(const short8*)((const char*)Tl +
            (((size_t)(m0 + i * 16 + lane15)) * 96 + (size_t)(kt - 8) * 32 +
             (size_t)g * 8) * 2);
    };

    loadB(0, 0);

#pragma unroll
    for (int kt = 0; kt < 11; ++kt) {
      const int cb = kt & 1;
      if (kt < 10) {
        loadB(cb ^ 1, kt + 1);
        if constexpr (TERMS == 3) {
          if (kt + 1 >= 8) loadTl((kt + 1) & 1, kt + 1);
        }
      }
      __builtin_amdgcn_sched_barrier(0);
#pragma unroll
      for (int i = 0; i < 4; ++i) {
        a_h[i] = *(const short8*)(Xh + kt * 4096 + offA[i]);
        if constexpr (TERMS == 3) {
          if (kt < 8)
            a_l[i] = *(const short8*)(Xl + kt * 4096 + offA[i]);
          else
            a_l[i] = tl_buf[kt & 1][i];
        }
      }
      __builtin_amdgcn_s_setprio(1);
#pragma unroll
      for (int i = 0; i < 4; ++i)
#pragma unroll
        for (int j = 0; j < 4; ++j) {
          acc[i][j] = __builtin_amdgcn_mfma_f32_16x16x32_bf16(a_h[i], b_h[cb][j], acc[i][j], 0, 0, 0);
          if constexpr (TERMS == 3) {
            acc[i][j] = __builtin_amdgcn_mfma_f32_16x16x32_bf16(a_h[i], b_l[cb][j], acc[i][j], 0, 0, 0);
            acc[i][j] = __builtin_amdgcn_mfma_f32_16x16x32_bf16(a_l[i], b_h[cb][j], acc[i][j], 0, 0, 0);
          }
        }
      __builtin_amdgcn_s_setprio(0);
      __builtin_amdgcn_sched_barrier(0);
    }

    if (L < 3) {
      __syncthreads();
#pragma unroll
      for (int j = 0; j < 4; ++j) {
        int o = w * 64 + j * 16 + lane15;
        float bv = bias_all[L * 256 + o];
        int kch = o >> 5;
        int s0 = (o >> 3) & 3;
        int e = o & 7;
#pragma unroll
        for (int i = 0; i < 4; ++i) {
          int mb = i * 16 + g * 4;
#pragma unroll
          for (int r = 0; r < 4; ++r) {
            int m = mb + r;
            float v = fmaxf(acc[i][j][r] + bv, 0.f);
            __hip_bfloat16 h = __float2bfloat16(v);
            int boff = kch * 4096 + m * 64 + ((s0 ^ ((m >> 1) & 3)) << 4) + e * 2;
            *(__hip_bfloat16*)(Xh + boff) = h;
            if constexpr (TERMS == 3)
              *(__hip_bfloat16*)(Xl + boff) = __float2bfloat16(v - __bfloat162float(h));
          }
        }
      }
      __syncthreads();
    } else {
#pragma unroll
      for (int j = 0; j < 4; ++j) {
        int o = w * 64 + j * 16 + lane15;
        float bv = bias_all[768 + o];
#pragma unroll
        for (int i = 0; i < 4; ++i) {
          int mb = i * 16 + g * 4;
#pragma unroll
          for (int r = 0; r < 4; ++r)
            PL[(size_t)(m0 + mb + r) * 128 + o] = acc[i][j][r] + bv;
        }
      }
    }
  }
}

// ---------------- scatter head outputs into ml (sel==nullptr: iota) ----------------
__global__ void scatter_kernel(const float* __restrict__ PL, const int* __restrict__ sel,
                               float* __restrict__ ml, int Nlev) {
  int t = blockIdx.x * 256 + threadIdx.x;
  if (t >= R_ * NPTS_ * K_) return;
  int k = t % K_;
  int rp = t / K_;
  int i = sel ? sel[rp] : (rp % NPTS_);
  int r = rp / NPTS_;
  ml[((size_t)r * K_ + k) * Nlev + i] = PL[(size_t)rp * 128 + k];
}

extern "C" void kernel_launch(void* const* d_in, const int* in_sizes, int n_in,
                              void* d_out, int out_size, void* d_ws, size_t ws_size,
                              hipStream_t stream) {
  (void)in_sizes; (void)n_in; (void)out_size; (void)ws_size;
  const float* feat = (const float*)d_in[0];
  const float* bboxes = (const float*)d_in[1];
  const int* labels = (const int*)d_in[2];
  const float* coarse = (const float*)d_in[3];
  const float* W1 = (const float*)d_in[4];
  const float* b1 = (const float*)d_in[5];
  const float* W2 = (const float*)d_in[6];
  const float* b2 = (const float*)d_in[7];
  const float* W3 = (const float*)d_in[8];
  const float* b3 = (const float*)d_in[9];
  const float* Wp = (const float*)d_in[10];
  const float* bp = (const float*)d_in[11];
  float* out = (float*)d_out;

  char* p = (char*)d_ws;
  auto alloc = [&](size_t bytes) { char* r = p; p += (bytes + 255) & ~(size_t)255; return r; };
  float* featT = (float*)alloc(16777216ull * 4);
  float* coarseT = (float*)alloc(254016ull * 4);
  float* ml28 = (float*)alloc(4064256ull * 4);
  float* ml56 = (float*)alloc(16257024ull * 4);
  float* PL = (float*)alloc(6422528ull * 4);
  int* sel = (int*)alloc(50176ull * 4);
  float* gtbuf = (float*)alloc(802816ull * 4);
  unsigned short* map = (unsigned short*)alloc(802816ull * 2);
  __hip_bfloat16* Xa_h = (__hip_bfloat16*)alloc(12845056ull * 2);
  __hip_bfloat16* Xa_l = (__hip_bfloat16*)alloc(12845056ull * 2);
  __hip_bfloat16* Ct_h = (__hip_bfloat16*)alloc(4816896ull * 2);
  __hip_bfloat16* Ct_l = (__hip_bfloat16*)alloc(4816896ull * 2);
  __hip_bfloat16* Wpk = (__hip_bfloat16*)alloc(720896ull * 2);
  float* bias_all = (float*)alloc(1024ull * 4);

  const int N = R_ * NPTS_;  // 50176
  const int B = R_ * K_;     // 5184

  transpose_feat_kernel<<<dim3(8, 8, 256), dim3(32, 8), 0, stream>>>(feat, featT);
  prep_all_kernel<<<1349, 256, 0, stream>>>(W1, W2, W3, Wp, b1, b2, b3, bp, coarse, Wpk, bias_all, coarseT);
  mapinit_kernel<<<3136, 256, 0, stream>>>(map);

  // ---- step 1: refine ALL 784 points (7->14->28 upsamples are dead: scatter
  //      overwrites the ENTIRE ml28, so they're skipped) ----
  sample_kernel<<<N, 256, 0, stream>>>(nullptr, bboxes, featT, coarseT, Xa_h, Xa_l, Ct_h, Ct_l, 28, 28);
  fused_head_kernel<3><<<784, 256, 0, stream>>>(Xa_h, Xa_l, Ct_h, Ct_l, Wpk, bias_all, PL);
  scatter_kernel<<<15876, 256, 0, stream>>>(PL, nullptr, ml28, 784);

  // ---- step 2: 28 -> 56, refine top-784 of 3136 (exact 3-term head) ----
  upsample2x_kernel<<<dim3(1, 14, B), dim3(64, 2), 0, stream>>>(ml28, ml56, 28, 28);
  topk_kernel<<<R_, 1024, 0, stream>>>(ml56, labels, nullptr, 3136, sel);
  sample_kernel<<<N, 256, 0, stream>>>(sel, bboxes, featT, coarseT, Xa_h, Xa_l, Ct_h, Ct_l, 56, 56);
  fused_head_kernel<3><<<784, 256, 0, stream>>>(Xa_h, Xa_l, Ct_h, Ct_l, Wpk, bias_all, PL);
  scatter_kernel<<<15876, 256, 0, stream>>>(PL, sel, ml56, 3136);

  // ---- step 3: gt-channel upsample -> topk -> head -> rank map -> fused
  //      final upsample+select into d_out (no 260MB RMW scatter) ----
  upsample2x_gt_kernel<<<dim3(1, 28, R_), dim3(64, 2), 0, stream>>>(ml56, labels, gtbuf);
  topk_kernel<<<R_, 1024, 0, stream>>>(nullptr, labels, gtbuf, 12544, sel);
  sample_kernel<<<N, 256, 0, stream>>>(sel, bboxes, featT, coarseT, Xa_h, Xa_l, Ct_h, Ct_l, 112, 112);
  fused_head_kernel<1><<<784, 256, 0, stream>>>(Xa_h, nullptr, Ct_h, nullptr, Wpk, bias_all, PL);
  mapbuild_kernel<<<196, 256, 0, stream>>>(sel, map);
  upsample2x_sel_kernel<<<dim3(1, 28, B), dim3(64, 2), 0, stream>>>(ml56, map, PL, out);
}